// Round 13
// baseline (708.955 us; speedup 1.0000x reference)
//
#include <hip/hip_runtime.h>
#include <hip/hip_bf16.h>
#include <math.h>

#define D_MODEL 384
#define D_STATE 64
#define D_INNER 768
#define HEADDIM 96
#define NHEADS 8
#define CONV_DIM 896
#define D_IN_PROJ 1672
#define XBC_LD 896         /* bf16 xBC row stride (X 0..767, B 768..831, C 832..895) */
#define BATCH 8
#define SEQ 1024
#define ROWS (BATCH*SEQ)   /* 8192 */
#define NUM_LAYERS 6
#define NC 32              /* chunks */
#define CHUNK 32           /* timesteps per chunk */
#define NPAD_IN 1792       /* 14 * 128 */
#define NPAD_OUT 384       /* 3 * 128  */
#define VP 776             /* padded Vsh row (shorts) */

/* fragment-tile layout: 16x16 tile stored as 256 elems, lane*4 + r
   (col = lane&15, row = (lane>>4)*4 + r)  -- matches MFMA C-layout      */
#define ZFT(rt,ct) (((size_t)(rt)*48 + (ct))*256)   /* 768-col blobs (z,y) */
#define RFT(rt,ct) (((size_t)(rt)*24 + (ct))*256)   /* 384-col blob (residual) */

typedef __hip_bfloat16 bf16;
using bf16x8_t = __attribute__((ext_vector_type(8))) short;
using f32x4_t  = __attribute__((ext_vector_type(4))) float;

__device__ __forceinline__ float softplus_f(float v){
  return v > 20.f ? v : log1pf(expf(v));
}
__device__ __forceinline__ float silu_f(float v){
  return v / (1.f + expf(-v));
}
__device__ __forceinline__ float bits_to_f(unsigned short u){
  union{unsigned u32; float f;} cv; cv.u32 = ((unsigned)u)<<16; return cv.f;
}
__device__ __forceinline__ unsigned short f_to_bits(float f){
  union{bf16 b; unsigned short u;} cv; cv.b = __float2bfloat16(f); return cv.u;
}

/* ------- weight transpose + fp32->bf16, all layers batched via grid.z ----------
   cscale (optional, per-layer stride K): fold norm_w into W_out columns.       */
__global__ void wconv_kernel(const float* __restrict__ W, bf16* __restrict__ Wt,
                             const float* __restrict__ cscale,
                             int K, int N, int Npad){
  __shared__ float tile[32][33];
  W  += (size_t)blockIdx.z*K*N;
  const float* cs = cscale ? (cscale + (size_t)blockIdx.z*K) : nullptr;
  Wt += (size_t)blockIdx.z*Npad*K;
  int kb = blockIdx.y*32, nb = blockIdx.x*32;
  int tx = threadIdx.x, ty = threadIdx.y;   /* 32 x 8 */
  #pragma unroll
  for (int r=0;r<32;r+=8){
    int k = kb+ty+r, n = nb+tx;
    float v = (k<K && n<N) ? W[(size_t)k*N+n] : 0.f;
    if (cs && k<K) v *= cs[k];
    tile[ty+r][tx] = v;
  }
  __syncthreads();
  #pragma unroll
  for (int r=0;r<32;r+=8){
    int n = nb+ty+r, k = kb+tx;
    if (n<Npad && k<K) Wt[(size_t)n*K+k] = __float2bfloat16(tile[tx][ty+r]);
  }
}

/* ---- x0 -> residual fragment blob (in d_out) ---------------------------------- */
__global__ __launch_bounds__(256) void xfrag_kernel(const float* __restrict__ x,
                                                    float* __restrict__ rf){
  const int tile = blockIdx.x*4 + (threadIdx.x>>6);   /* 12288 tiles */
  const int lane = threadIdx.x & 63;
  const int rt = tile/24, ct = tile%24;
  const int col = ct*16 + (lane&15);
  const int r0  = rt*16 + (lane>>4)*4;
  f32x4_t v;
  #pragma unroll
  for (int r=0;r<4;r++) v[r] = x[(size_t)(r0+r)*D_MODEL + col];
  *(f32x4_t*)(rf + RFT(rt,ct) + lane*4) = v;
}

/* ---------------- LayerNorm (layer 0 only): one WAVE per row of 384 -> bf16 ---- */
__global__ __launch_bounds__(256) void ln_kernel(const float* __restrict__ x, const float* __restrict__ w,
                          const float* __restrict__ b, unsigned short* __restrict__ o){
  const int wave = threadIdx.x >> 6, lane = threadIdx.x & 63;
  const int r = blockIdx.x*4 + wave;
  const float* xr = x + (size_t)r*D_MODEL;
  float2 v[3];
  float s = 0.f, sq = 0.f;
  #pragma unroll
  for (int e=0;e<3;e++){
    v[e] = *(const float2*)(xr + e*128 + lane*2);
    s  += v[e].x + v[e].y;
    sq += v[e].x*v[e].x + v[e].y*v[e].y;
  }
  #pragma unroll
  for (int off=1; off<64; off<<=1){
    s  += __shfl_xor(s, off);
    sq += __shfl_xor(sq, off);
  }
  float mu  = s*(1.f/D_MODEL);
  float var = sq*(1.f/D_MODEL) - mu*mu;
  var = var < 0.f ? 0.f : var;
  float rstd = rsqrtf(var + 1e-12f);
  unsigned short* orow = o + (size_t)r*D_MODEL;
  #pragma unroll
  for (int e=0;e<3;e++){
    int c = e*128 + lane*2;
    float2 wv = *(const float2*)(w + c);
    float2 bv = *(const float2*)(b + c);
    ushort2 ov;
    ov.x = f_to_bits((v[e].x-mu)*rstd*wv.x + bv.x);
    ov.y = f_to_bits((v[e].y-mu)*rstd*wv.y + bv.y);
    *(ushort2*)(orow + c) = ov;
  }
}

/* ------- bf16 MFMA GEMM (in-proj): 256x128 tile, BK=64, XOR-swizzled LDS -------
   448 blocks = one full round at 2 blocks/CU.                                 */
__global__ __launch_bounds__(256, 2) void gemm_in(
    const unsigned short* __restrict__ A,   /* M x 384 bf16, row-major */
    const unsigned short* __restrict__ Bt,  /* Npad x K bf16 (W_in transposed) */
    unsigned short* __restrict__ zfrag,     /* fragment blob, 48 col tiles */
    unsigned short* __restrict__ xbc,       /* M x XBC_LD bf16 */
    float* __restrict__ dtraw,              /* M x 8 fp32 */
    int K){
  __shared__ __align__(16) unsigned short smem[24576];  /* 48 KB: As 256x64 | Bs 128x64 */
  unsigned short* Bs = smem + 16384;
  const int tid = threadIdx.x;
  const int wave = tid >> 6, lane = tid & 63;
  const int lq = lane >> 4, lm = lane & 15;
  /* XCD swizzle: 448 blocks = 8 XCDs x 56 */
  const int lin = blockIdx.y*14 + blockIdx.x;
  const int nl  = (lin & 7)*56 + (lin >> 3);
  const int m0 = (nl / 14) * 256, n0 = (nl % 14) * 128;
  const int wm = (wave >> 1) * 128, wn = (wave & 1) * 64;
  f32x4_t acc[8][4];
  #pragma unroll
  for (int i=0;i<8;i++)
    #pragma unroll
    for (int j=0;j<4;j++)
      acc[i][j] = (f32x4_t){0.f,0.f,0.f,0.f};

  for (int k0 = 0; k0 < K; k0 += 64){
    if (k0) __syncthreads();
    #pragma unroll
    for (int q=0;q<8;q++){            /* A: 256 rows x 128 B */
      int o = q*4096 + wave*1024 + lane*16;
      int m = o >> 7;
      int kbs = (o & 127) ^ ((m & 7) << 4);
      const unsigned short* ga = A + (size_t)(m0+m)*K + k0 + (kbs>>1);
      __builtin_amdgcn_global_load_lds(
          (const __attribute__((address_space(1))) void*)ga,
          (__attribute__((address_space(3))) void*)((char*)smem + o), 16, 0, 0);
    }
    #pragma unroll
    for (int q=0;q<4;q++){            /* B: 128 rows x 128 B */
      int o = q*4096 + wave*1024 + lane*16;
      int n = o >> 7;
      int kbs = (o & 127) ^ ((n & 7) << 4);
      const unsigned short* gb = Bt + (size_t)(n0+n)*K + k0 + (kbs>>1);
      __builtin_amdgcn_global_load_lds(
          (const __attribute__((address_space(1))) void*)gb,
          (__attribute__((address_space(3))) void*)((char*)smem + 32768 + o), 16, 0, 0);
    }
    __syncthreads();
    #pragma unroll
    for (int kk=0;kk<2;kk++){
      bf16x8_t af[8], bfv[4];
      #pragma unroll
      for (int i=0;i<8;i++){
        int row = wm + i*16 + lm;
        int bo = (kk*64 + lq*16) ^ ((row & 7) << 4);
        af[i] = *(const bf16x8_t*)(smem + row*64 + (bo>>1));
      }
      #pragma unroll
      for (int j=0;j<4;j++){
        int row = wn + j*16 + lm;
        int bo = (kk*64 + lq*16) ^ ((row & 7) << 4);
        bfv[j] = *(const bf16x8_t*)(Bs + row*64 + (bo>>1));
      }
      #pragma unroll
      for (int i=0;i<8;i++)
        #pragma unroll
        for (int j=0;j<4;j++)
          acc[i][j] = __builtin_amdgcn_mfma_f32_16x16x32_bf16(af[i], bfv[j], acc[i][j], 0, 0, 0);
    }
  }

  if (n0 == 1664){
    /* dt block: local cols 0..7 are dt (fp32 direct); rest is padding */
    if ((wave & 1) == 0 && lm < 8){
      #pragma unroll
      for (int i=0;i<8;i++){
        int row = m0 + wm + i*16 + lq*4;
        #pragma unroll
        for (int r=0;r<4;r++)
          dtraw[(size_t)(row+r)*8 + lm] = acc[i][0][r];
      }
    }
    return;
  }
  if (n0 < 768){
    /* z tiles: direct fragment-blob stores, 8B/lane coalesced */
    #pragma unroll
    for (int i=0;i<8;i++){
      int rt = (m0 + wm + i*16) >> 4;
      #pragma unroll
      for (int j=0;j<4;j++){
        int ct = (n0 + wn + j*16) >> 4;
        ushort4 v4;
        v4.x = f_to_bits(acc[i][j][0]); v4.y = f_to_bits(acc[i][j][1]);
        v4.z = f_to_bits(acc[i][j][2]); v4.w = f_to_bits(acc[i][j][3]);
        *(ushort4*)(zfrag + ZFT(rt,ct) + lane*4) = v4;
      }
    }
    return;
  }
  /* xBC: row-major via LDS bounce, two 128-row half-passes */
  #pragma unroll
  for (int h=0;h<2;h++){
    __syncthreads();
    if ((wave >> 1) == h){
      #pragma unroll
      for (int i=0;i<8;i++){
        int rl = i*16 + lq*4;
        #pragma unroll
        for (int j=0;j<4;j++){
          int cl = wn + j*16 + lm;
          #pragma unroll
          for (int r=0;r<4;r++)
            smem[(rl+r)*136 + cl] = f_to_bits(acc[i][j][r]);
        }
      }
    }
    __syncthreads();
    int row = tid >> 1;
    int cbase = (tid & 1) * 64;
    size_t gb = (size_t)(m0 + h*128 + row) * XBC_LD + (n0 - 768) + cbase;
    #pragma unroll
    for (int k=0;k<8;k++)
      *(bf16x8_t*)(xbc + gb + k*8) = *(const bf16x8_t*)&smem[row*136 + cbase + k*8];
  }
}

/* ==== fused conv(k=4)+silu + dt/softplus + cumsum + chunked-SSD matmuls ========
   Conv is a SINGLE 35-step pass: waves 0-2 do X (1 col/thread, global reads);
   wave 3 does B and C together (dual rolling windows from LDS stage).         */
__global__ __launch_bounds__(256, 4) void fused_scan_kernel(
    const unsigned short* __restrict__ xbc, const float* __restrict__ dtraw,
    const float* __restrict__ cw, const float* __restrict__ cb,
    const float* __restrict__ dt_bias, const float* __restrict__ A_log,
    const float* __restrict__ D_skip,
    float* __restrict__ cumb, float* __restrict__ Dc,
    unsigned short* __restrict__ Cb, unsigned short* __restrict__ Sb,
    unsigned short* __restrict__ yfrag){
  __shared__ __align__(16) unsigned short Ssh[35*128];   /* B/C stage; Msh alias */
  __shared__ __align__(16) unsigned short XshT[192*40];  /* X^T[p_local][t] */
  __shared__ __align__(16) unsigned short BshT[64*40];   /* B^T[n][t] */
  __shared__ __align__(16) unsigned short Bsh[32*72];    /* B[t][n] */
  __shared__ __align__(16) unsigned short Csh[32*72];    /* C[t][n] */
  __shared__ float dtsh[64], Lsh[64], wsh[64];
  unsigned short* Msh = Ssh;                             /* 2*32*40 ushorts, post-conv */
  const int tid = threadIdx.x;
  const int bid = blockIdx.x;
  const int hp = bid & 3, c = (bid >> 2) & 31, b = bid >> 7;
  const int h_base = hp*2;
  const int t0 = c*CHUNK;

  /* ---- dt + raw log-decay for this block's 2 heads ---- */
  if (tid < 64){
    int hi = tid >> 5, t = tid & 31;
    int hg = h_base + hi;
    float raw = dtraw[(size_t)(b*SEQ + t0 + t)*8 + hg];
    float dtv_ = softplus_f(raw + dt_bias[hg]);
    dtsh[tid] = dtv_;
    Lsh[tid]  = dtv_ * (-expf(A_log[hg]));
  }

  /* ---- stage B/C conv input: 35 rows x 128 cols, 16B loads ---- */
  {
    const size_t rowbase = (size_t)b*SEQ*XBC_LD;
    for (int i = tid; i < 35*16; i += 256){
      int row = i/16, seg = i%16;
      int l = t0 - 3 + row;
      bf16x8_t v = {0,0,0,0,0,0,0,0};
      if (l >= 0)
        v = *(const bf16x8_t*)(xbc + rowbase + (size_t)l*XBC_LD + 768 + seg*8);
      *(bf16x8_t*)&Ssh[row*128 + seg*8] = v;
    }
  }
  __syncthreads();

  /* ---- conv: single pass. tids 0-191: X; tids 192-255: B and C (dual) ---- */
  if (tid < 192){
    int cch = h_base*96 + tid;
    float4 w4 = *(const float4*)(cw + cch*4);
    float bias = cb[cch];
    const unsigned short* src = xbc + (size_t)b*SEQ*XBC_LD + cch;  /* X: cch==gcol */
    float v0=0.f,v1=0.f,v2=0.f,v3=0.f;
    unsigned prev = 0;
    for (int t=-3; t<32; t++){
      int l = t0 + t;
      float nv = (l >= 0) ? bits_to_f(src[(size_t)l*XBC_LD]) : 0.f;
      v0=v1; v1=v2; v2=v3; v3=nv;
      if (t < 0) continue;
      float a = silu_f(bias + w4.x*v0 + w4.y*v1 + w4.z*v2 + w4.w*v3);
      unsigned short ub = f_to_bits(a);
      if (t & 1) *(unsigned*)&XshT[tid*40 + (t-1)] = prev | ((unsigned)ub<<16);
      else prev = ub;
    }
  } else {
    int n = tid - 192;                         /* 0..63 */
    int cchB = D_INNER + n, cchC = D_INNER + D_STATE + n;
    float4 wB = *(const float4*)(cw + cchB*4);
    float4 wC = *(const float4*)(cw + cchC*4);
    float bB = cb[cchB], bC = cb[cchC];
    float b0=0.f,b1=0.f,b2=0.f,b3=0.f;
    float c0=0.f,c1=0.f,c2=0.f,c3=0.f;
    unsigned prevB = 0;
    for (int t=-3; t<32; t++){
      float nb = bits_to_f(Ssh[(t+3)*128 + n]);
      float nc = bits_to_f(Ssh[(t+3)*128 + 64 + n]);
      b0=b1; b1=b2; b2=b3; b3=nb;
      c0=c1; c1=c2; c2=c3; c3=nc;
      if (t < 0) continue;
      float aB = silu_f(bB + wB.x*b0 + wB.y*b1 + wB.z*b2 + wB.w*b3);
      float aC = silu_f(bC + wC.x*c0 + wC.y*c1 + wC.z*c2 + wC.w*c3);
      unsigned short uB = f_to_bits(aB);
      Bsh[t*72 + n] = uB;
      Csh[t*72 + n] = f_to_bits(aC);
      if (t & 1) *(unsigned*)&BshT[n*40 + (t-1)] = prevB | ((unsigned)uB<<16);
      else prevB = uB;
    }
  }
  __syncthreads();

  /* ---- wave-parallel cumsum of log-decay (Hillis-Steele, 32-lane segments) ---- */
  if (tid < 64){
    int hg = h_base + (tid >> 5);
    float L = Lsh[tid];
    #pragma unroll
    for (int off=1; off<32; off<<=1){
      float nv = __shfl_up(L, off, 32);
      if ((tid & 31) >= off) L += nv;
    }
    Lsh[tid] = L;
    cumb[((size_t)((b*NC + c)*NHEADS) + hg)*CHUNK + (tid & 31)] = __expf(L);
    float Ltot = __shfl(L, 31, 32);
    if ((tid & 31) == 31) Dc[(b*NHEADS + hg)*NC + c] = __expf(L);
    wsh[tid] = __expf(Ltot - L) * dtsh[tid];
  }
  __syncthreads();

  const int wave = tid >> 6, lane = tid & 63;
  const int lq = lane >> 4, lm = lane & 15;
  const f32x4_t zero = (f32x4_t){0.f,0.f,0.f,0.f};

  /* ---- waves 0,1: G = C.B^T then M~ (D-skip on diagonal); waves 2,3: Cb out ---- */
  if (wave < 2){
    f32x4_t G[2][2];
    #pragma unroll
    for (int i=0;i<2;i++){ G[i][0]=zero; G[i][1]=zero; }
    #pragma unroll
    for (int kt=0; kt<2; kt++){
      bf16x8_t ca[2], bb[2];
      #pragma unroll
      for (int ti=0;ti<2;ti++)
        ca[ti] = *(const bf16x8_t*)&Csh[(lm+ti*16)*72 + kt*32 + lq*8];
      #pragma unroll
      for (int si=0;si<2;si++)
        bb[si] = *(const bf16x8_t*)&Bsh[(lm+si*16)*72 + kt*32 + lq*8];
      #pragma unroll
      for (int ti=0;ti<2;ti++)
        #pragma unroll
        for (int si=0;si<2;si++)
          G[ti][si] = __builtin_amdgcn_mfma_f32_16x16x32_bf16(ca[ti], bb[si], G[ti][si], 0,0,0);
    }
    int hi = wave;
    float Dk = D_skip[h_base + hi];
    float Lss[2], dts[2];
    #pragma unroll
    for (int si=0;si<2;si++){ Lss[si]=Lsh[hi*32+si*16+lm]; dts[si]=dtsh[hi*32+si*16+lm]; }
    #pragma unroll
    for (int ti=0;ti<2;ti++){
      #pragma unroll
      for (int r=0;r<4;r++){
        int t = ti*16 + lq*4 + r;
        float Lt = Lsh[hi*32 + t];
        #pragma unroll
        for (int si=0;si<2;si++){
          int s = si*16 + lm;
          float m = 0.f;
          if (s <= t){
            m = G[ti][si][r]*__expf(Lt - Lss[si])*dts[si];
            if (s == t) m += Dk;
          }
          Msh[hi*1280 + t*40 + s] = f_to_bits(m);
        }
      }
    }
  } else if (hp == 0){
    int lt = tid - 128;
    for (int i = lt; i < 512; i += 128){
      int t = i >> 4, q = i & 15;
      *(ushort4*)(Cb + ((size_t)(b*SEQ) + t0 + t)*D_STATE + q*4) =
          *(const ushort4*)&Csh[t*72 + q*4];
    }
  }
  __syncthreads();

  /* ---- compute: wave -> (head hi = wave&1, pt-half = wave>>1) ---- */
  {
    int hi = wave & 1, hg = h_base + hi;
    int ptb = (wave >> 1)*3;
    const int rt0 = (b*SEQ + t0) >> 4;
    bf16x8_t mf[2];
    #pragma unroll
    for (int tt=0;tt<2;tt++)
      mf[tt] = *(const bf16x8_t*)&Msh[hi*1280 + (lm+tt*16)*40 + lq*8];
    float wv[8];
    #pragma unroll
    for (int j=0;j<8;j++) wv[j] = wsh[hi*32 + lq*8 + j];
    bf16x8_t bw[4];
    #pragma unroll
    for (int nt=0;nt<4;nt++){
      bf16x8_t raw = *(const bf16x8_t*)&BshT[(lm+nt*16)*40 + lq*8];
      #pragma unroll
      for (int j=0;j<8;j++)
        bw[nt][j] = (short)f_to_bits(bits_to_f((unsigned short)raw[j]) * wv[j]);
    }
    const size_t sbase = ((size_t)((b*NC + c)*NHEADS) + hg)*HEADDIM*D_STATE;
    #pragma unroll
    for (int pp=0; pp<3; pp++){
      int pt = ptb + pp;
      bf16x8_t xf = *(const bf16x8_t*)&XshT[(hi*96 + pt*16 + lm)*40 + lq*8];
      /* Y1 (+ D*x via diagonal) -> fragment blob, 8B/lane */
      #pragma unroll
      for (int tt=0;tt<2;tt++){
        f32x4_t a = __builtin_amdgcn_mfma_f32_16x16x32_bf16(mf[tt], xf, zero, 0,0,0);
        ushort4 y4;
        y4.x = f_to_bits(a[0]); y4.y = f_to_bits(a[1]);
        y4.z = f_to_bits(a[2]); y4.w = f_to_bits(a[3]);
        *(ushort4*)(yfrag + ZFT(rt0+tt, hg*6+pt) + lane*4) = y4;
      }
      /* S = X^T @ (w.B) */
      #pragma unroll
      for (int nt=0;nt<4;nt++){
        f32x4_t s = __builtin_amdgcn_mfma_f32_16x16x32_bf16(xf, bw[nt], zero, 0,0,0);
        #pragma unroll
        for (int r=0;r<4;r++){
          int p = pt*16 + lq*4 + r;
          Sb[sbase + (size_t)p*D_STATE + nt*16 + lm] = f_to_bits(s[r]);
        }
      }
    }
  }
}

/* ---- sequential chunk combine on bf16 S (in-place -> Hin), 8-deep prefetch ----
   1 elem/thread -> 393216 threads (6 blocks/CU, 24 waves/CU of TLP)           */
__global__ __launch_bounds__(256) void combine_kernel(
    unsigned short* __restrict__ S, const float* __restrict__ Dc){
  int g = blockIdx.x*256 + threadIdx.x;     /* (b,h,p,n): 8*8*96*64 = 393216 */
  int n  = g & 63;
  int p  = (g >> 6) % 96;
  int h  = (g / (64*96)) & 7;
  int b  = g / (64*96*8);
  const float* Dp = Dc + (size_t)(b*NHEADS + h)*NC;
  const size_t cstride = (size_t)NHEADS*HEADDIM*D_STATE;   /* 49152 */
  size_t base = (((size_t)(b*NC)*NHEADS + h)*HEADDIM + p)*D_STATE + n;
  float H = 0.f;
  #pragma unroll 1
  for (int c=0;c<NC;c+=8){
    unsigned short s[8];
    #pragma unroll
    for (int q=0;q<8;q++)
      s[q] = S[base + (size_t)q*cstride];
    #pragma unroll
    for (int q=0;q<8;q++){
      S[base] = f_to_bits(H);
      H = fmaf(Dp[c+q], H, bits_to_f(s[q]));
      base += cstride;
    }
  }
}

/* ==== fused tail: y+cum*(C@Hin^T), silu(z) gate, RMS (folded), @W_out into
   residual fragment blob, next-layer LN -> hnb. Last layer: row-major.
   Phase 2/3: wave -> (row-tile w&1, col-group w>>1), full K per wave -- no
   partial-sum park/add barriers, all 16 waves active in phase 3.            == */
__global__ __launch_bounds__(1024, 4) void hinfuse_out_kernel(
    const unsigned short* __restrict__ Cb, const unsigned short* __restrict__ Hinb,
    const float* __restrict__ cumb, const unsigned short* __restrict__ zfrag,
    const unsigned short* __restrict__ yfrag,
    const unsigned short* __restrict__ Wot,   /* NPAD_OUT x D_INNER bf16 (norm_w-scaled) */
    float* __restrict__ outf,                 /* residual fragment blob / final out */
    const float* __restrict__ lnw, const float* __restrict__ lnb,
    unsigned short* __restrict__ hnb,         /* next-layer LN out, bf16 */
    int last){
  __shared__ __align__(16) unsigned short Vsh[32*VP];     /* 49664 B */
  __shared__ float rowsqW[16][32];
  __shared__ float rowsq[32];
  __shared__ float rsumW[8][32], rsqW[8][32], mu_s[32], rs_s[32];
  const int tid = threadIdx.x;
  const int c = blockIdx.x & 31, b = blockIdx.x >> 5;
  const int t0 = c*CHUNK;
  const int rt0 = (b*SEQ + t0) >> 4;
  const int wave = tid >> 6, lane = tid & 63;
  const int lq = lane >> 4, lm = lane & 15;
  const f32x4_t zero = (f32x4_t){0.f,0.f,0.f,0.f};

  /* ---- phase 1: V = (y + cum*C@Hin^T)*silu(z) -> Vsh; 2 waves/head (pt-halves) - */
  {
    float sql[2][4] = {};
    const int h = wave >> 1;
    const int pt0 = (wave & 1)*3;
    float cumv[2][4];
    {
      const float* cbp = cumb + ((size_t)((b*NC + c)*NHEADS) + h)*CHUNK;
      #pragma unroll
      for (int tt=0;tt<2;tt++)
        #pragma unroll
        for (int r=0;r<4;r++)
          cumv[tt][r] = cbp[tt*16 + lq*4 + r];
    }
    const unsigned short* Hb = Hinb + ((size_t)((b*NC + c)*NHEADS) + h)*HEADDIM*D_STATE;
    bf16x8_t ca[2][2];
    #pragma unroll
    for (int tt=0;tt<2;tt++)
      #pragma unroll
      for (int kt=0;kt<2;kt++)
        ca[tt][kt] = *(const bf16x8_t*)(Cb +
            ((size_t)(b*SEQ) + t0 + tt*16 + lm)*D_STATE + kt*32 + lq*8);
    #pragma unroll
    for (int pp=0; pp<3; pp++){
      int pt = pt0 + pp;
      bf16x8_t hf0 = *(const bf16x8_t*)&Hb[(size_t)(lm+pt*16)*D_STATE + lq*8];
      bf16x8_t hf1 = *(const bf16x8_t*)&Hb[(size_t)(lm+pt*16)*D_STATE + 32 + lq*8];
      f32x4_t acc[2];
      ushort4 yf4[2], zf4[2];
      #pragma unroll
      for (int tt=0;tt<2;tt++){
        yf4[tt] = *(const ushort4*)(yfrag + ZFT(rt0+tt, h*6+pt) + lane*4);
        zf4[tt] = *(const ushort4*)(zfrag + ZFT(rt0+tt, h*6+pt) + lane*4);
        acc[tt] = __builtin_amdgcn_mfma_f32_16x16x32_bf16(ca[tt][0], hf0, zero, 0,0,0);
        acc[tt] = __builtin_amdgcn_mfma_f32_16x16x32_bf16(ca[tt][1], hf1, acc[tt], 0,0,0);
      }
      int pcol = h*HEADDIM + pt*16 + lm;
      #pragma unroll
      for (int tt=0;tt<2;tt++){
        const unsigned short* yp = (const unsigned short*)&yf4[tt];
        const unsigned short* zp = (const unsigned short*)&zf4[tt];
        #pragma unroll
        for (int r=0;r<4;r++){
          int t = tt*16 + lq*4 + r;
          float yv = bits_to_f(yp[r]) + cumv[tt][r]*acc[tt][r];
          float z  = bits_to_f(zp[r]);
          float v  = yv * silu_f(z);
          Vsh[t*VP + pcol] = f_to_bits(v);
          sql[tt][r] += v*v;
        }
      }
    }
    /* per-wave slots: no atomics, no init */
    #pragma unroll
    for (int tt=0;tt<2;tt++)
      #pragma unroll
      for (int r=0;r<4;r++){
        float v = sql[tt][r];
        v += __shfl_xor(v,1); v += __shfl_xor(v,2);
        v += __shfl_xor(v,4); v += __shfl_xor(v,8);
        if (lm == 0) rowsqW[wave][tt*16 + lq*4 + r] = v;
      }
  }
  __syncthreads();
  if (tid < 32){
    float s = 0.f;
    #pragma unroll
    for (int w=0;w<16;w++) s += rowsqW[w][tid];
    rowsq[tid] = rsqrtf(s*(1.f/D_INNER) + 1e-5f);
  }
  __syncthreads();

  /* ---- phase 2: delta(32x384) = Vsh(32x768) @ Wot^T; wave->(rt=w&1, cg=w>>1) -- */
  const int rt = wave & 1, cg = wave >> 1;
  const int wn = cg*48;
  f32x4_t acc[3] = {zero, zero, zero};
  {
    bf16x8_t afA, afB, bfA[3], bfB[3];
#define LOADK(af_, bf_, K0) { \
    af_ = *(const bf16x8_t*)&Vsh[(rt*16 + lm)*VP + (K0) + lq*8]; \
    bf_[0] = *(const bf16x8_t*)(Wot + (size_t)(wn      + lm)*D_INNER + (K0) + lq*8); \
    bf_[1] = *(const bf16x8_t*)(Wot + (size_t)(wn + 16 + lm)*D_INNER + (K0) + lq*8); \
    bf_[2] = *(const bf16x8_t*)(Wot + (size_t)(wn + 32 + lm)*D_INNER + (K0) + lq*8); \
  }
    LOADK(afA, bfA, 0)
    #pragma unroll
    for (int ks=0; ks<24; ks+=2){
      LOADK(afB, bfB, (ks+1)*32)
      #pragma unroll
      for (int j=0;j<3;j++)
        acc[j] = __builtin_amdgcn_mfma_f32_16x16x32_bf16(afA, bfA[j], acc[j], 0,0,0);
      if (ks+2 < 24) LOADK(afA, bfA, (ks+2)*32)
      #pragma unroll
      for (int j=0;j<3;j++)
        acc[j] = __builtin_amdgcn_mfma_f32_16x16x32_bf16(afB, bfB[j], acc[j], 0,0,0);
    }
#undef LOADK
  }

  /* ---- phase 3 (all 16 waves): rms scale + residual RMW; LN -> hnb / row-major  */
  float ov[3][4];
  #pragma unroll
  for (int j=0;j<3;j++){
    f32x4_t rv = *(const f32x4_t*)(outf + RFT(rt0+rt, cg*3+j) + lane*4);
    #pragma unroll
    for (int r=0;r<4;r++){
      float rms = rowsq[rt*16 + lq*4 + r];
      ov[j][r] = rv[r] + acc[j][r]*rms;
    }
  }

  if (last){
    __syncthreads();   /* all fragment reads done before row-major writes to slab */
    #pragma unroll
    for (int r=0;r<4;r++){
      size_t row = (size_t)(b*SEQ) + t0 + rt*16 + lq*4 + r;
      #pragma unroll
      for (int j=0;j<3;j++)
        outf[row*D_MODEL + wn + j*16 + lm] = ov[j][r];
    }
    return;
  }

  #pragma unroll
  for (int j=0;j<3;j++){
    f32x4_t rv;
    #pragma unroll
    for (int r=0;r<4;r++) rv[r] = ov[j][r];
    *(f32x4_t*)(outf + RFT(rt0+rt, cg*3+j) + lane*4) = rv;
  }
  /* LN stats into per-wave slots (no atomics); (cg,t) written by one wave */
  #pragma unroll
  for (int r=0;r<4;r++){
    int t = rt*16 + lq*4 + r;
    float s = 0.f, sq = 0.f;
    #pragma unroll
    for (int j=0;j<3;j++){ float o = ov[j][r]; s += o; sq += o*o; }
    s  += __shfl_xor(s,1);  s  += __shfl_xor(s,2);  s  += __shfl_xor(s,4);  s  += __shfl_xor(s,8);
    sq += __shfl_xor(sq,1); sq += __shfl_xor(sq,2); sq += __shfl_xor(sq,4); sq += __shfl_xor(sq,8);
    if (lm == 0){ rsumW[cg][t] = s; rsqW[cg][t] = sq; }
  }
  __syncthreads();
  if (tid < 32){
    float s = 0.f, sq = 0.f;
    #pragma unroll
    for (int w=0;w<8;w++){ s += rsumW[w][tid]; sq += rsqW[w][tid]; }
    float mu  = s*(1.f/D_MODEL);
    float var = sq*(1.f/D_MODEL) - mu*mu;
    var = var < 0.f ? 0.f : var;
    mu_s[tid] = mu;
    rs_s[tid] = rsqrtf(var + 1e-12f);
  }
  __syncthreads();
  #pragma unroll
  for (int r=0;r<4;r++){
    int t = rt*16 + lq*4 + r;
    size_t row = (size_t)(b*SEQ) + t0 + t;
    float mu = mu_s[t], rs = rs_s[t];
    #pragma unroll
    for (int j=0;j<3;j++){
      int n = wn + j*16 + lm;
      hnb[row*D_MODEL + n] = f_to_bits((ov[j][r]-mu)*rs*lnw[n] + lnb[n]);
    }
  }
}

extern "C" void kernel_launch(void* const* d_in, const int* in_sizes, int n_in,
                              void* d_out, int out_size, void* d_ws, size_t ws_size,
                              hipStream_t stream){
  const float* x0      = (const float*)d_in[0];
  const float* ln_w    = (const float*)d_in[1];
  const float* ln_b    = (const float*)d_in[2];
  const float* W_in    = (const float*)d_in[3];
  const float* conv_w  = (const float*)d_in[4];
  const float* conv_b  = (const float*)d_in[5];
  const float* dt_bias = (const float*)d_in[6];
  const float* A_log   = (const float*)d_in[7];
  const float* D_skip  = (const float*)d_in[8];
  const float* norm_w  = (const float*)d_in[9];
  const float* W_out   = (const float*)d_in[10];
  float* out = (float*)d_out;

  /* workspace (float units), ~85 MB */
  float* p    = (float*)d_ws;
  unsigned short* xbc   = (unsigned short*)p; p += (size_t)ROWS*XBC_LD/2;
  float* dtraw = p;  p += (size_t)ROWS*8;
  float* cumb  = p;  p += (size_t)BATCH*NHEADS*SEQ;
  float* Dc    = p;  p += (size_t)BATCH*NHEADS*NC;
  unsigned short* yfrag = (unsigned short*)p; p += (size_t)ROWS*D_INNER/2;
  unsigned short* zfrag = (unsigned short*)p; p += (size_t)ROWS*D_INNER/2;
  unsigned short* hnb   = (unsigned short*)p; p += (size_t)ROWS*D_MODEL/2;
  unsigned short* Sb    = (unsigned short*)p; p += (size_t)BATCH*NC*NHEADS*HEADDIM*D_STATE/2;
  unsigned short* Cb    = (unsigned short*)p; p += (size_t)ROWS*D_STATE/2;
  bf16* Wt  = (bf16*)p; p += (size_t)NUM_LAYERS*NPAD_IN*D_MODEL/2;
  bf16* Wot = (bf16*)p;

  wconv_kernel<<<dim3(NPAD_IN/32, D_MODEL/32, NUM_LAYERS), dim3(32,8), 0, stream>>>(
      W_in, Wt, nullptr, D_MODEL, D_IN_PROJ, NPAD_IN);
  /* fold norm_w into W_out rows (k = D_INNER dim) */
  wconv_kernel<<<dim3(NPAD_OUT/32, D_INNER/32, NUM_LAYERS), dim3(32,8), 0, stream>>>(
      W_out, Wot, norm_w, D_INNER, D_MODEL, NPAD_OUT);

  /* residual stream -> fragment blob inside d_out; layer-0 LN from x0 */
  xfrag_kernel<<<(ROWS/16)*24/4, 256, 0, stream>>>(x0, out);
  ln_kernel<<<ROWS/4,256,0,stream>>>(x0, ln_w, ln_b, hnb);

  for (int i=0;i<NUM_LAYERS;i++){
    int last = (i == NUM_LAYERS-1);
    gemm_in<<<dim3(14, ROWS/256), 256, 0, stream>>>(
        (const unsigned short*)hnb, (const unsigned short*)(Wt + (size_t)i*NPAD_IN*D_MODEL),
        zfrag, xbc, dtraw, D_MODEL);
    fused_scan_kernel<<<BATCH*NC*4, 256, 0, stream>>>(
        xbc, dtraw, conv_w + (size_t)i*CONV_DIM*4, conv_b + (size_t)i*CONV_DIM,
        dt_bias+(size_t)i*NHEADS, A_log+(size_t)i*NHEADS, D_skip+(size_t)i*NHEADS,
        cumb, Dc, Cb, Sb, yfrag);
    combine_kernel<<<(BATCH*NHEADS*HEADDIM*64)/256, 256, 0, stream>>>(Sb, Dc);
    hinfuse_out_kernel<<<BATCH*NC, 1024, 0, stream>>>(
        Cb, Sb, cumb, zfrag, yfrag,
        (const unsigned short*)(Wot + (size_t)i*NPAD_OUT*D_INNER), out,
        ln_w + (size_t)(last ? i : i+1)*D_MODEL,
        ln_b + (size_t)(last ? i : i+1)*D_MODEL,
        hnb, last);
  }
}

// Round 15
// 624.297 us; speedup vs baseline: 1.1356x; 1.1356x over previous
//
#include <hip/hip_runtime.h>
#include <hip/hip_bf16.h>
#include <math.h>

#define D_MODEL 384
#define D_STATE 64
#define D_INNER 768
#define HEADDIM 96
#define NHEADS 8
#define CONV_DIM 896
#define D_IN_PROJ 1672
#define XBC_LD 896         /* bf16 xBC row stride (X 0..767, B 768..831, C 832..895) */
#define BATCH 8
#define SEQ 1024
#define ROWS (BATCH*SEQ)   /* 8192 */
#define NUM_LAYERS 6
#define NC 32              /* chunks */
#define CHUNK 32           /* timesteps per chunk */
#define NPAD_IN 1792       /* 14 * 128 */
#define NPAD_OUT 384       /* 3 * 128  */
#define VP 776             /* padded Vsh row (shorts) */

/* fragment-tile layout: 16x16 tile stored as 256 elems, lane*4 + r
   (col = lane&15, row = (lane>>4)*4 + r)  -- matches MFMA C-layout      */
#define ZFT(rt,ct) (((size_t)(rt)*48 + (ct))*256)   /* 768-col blobs (z,y) */
#define RFT(rt,ct) (((size_t)(rt)*24 + (ct))*256)   /* 384-col blob (residual) */

typedef __hip_bfloat16 bf16;
using bf16x8_t = __attribute__((ext_vector_type(8))) short;
using f32x4_t  = __attribute__((ext_vector_type(4))) float;

__device__ __forceinline__ float softplus_f(float v){
  return v > 20.f ? v : log1pf(expf(v));
}
__device__ __forceinline__ float silu_f(float v){
  return v / (1.f + expf(-v));
}
__device__ __forceinline__ float bits_to_f(unsigned short u){
  union{unsigned u32; float f;} cv; cv.u32 = ((unsigned)u)<<16; return cv.f;
}
__device__ __forceinline__ unsigned short f_to_bits(float f){
  union{bf16 b; unsigned short u;} cv; cv.b = __float2bfloat16(f); return cv.u;
}

/* ------- weight transpose + fp32->bf16, all layers batched via grid.z ----------
   cscale (optional, per-layer stride K): fold norm_w into W_out columns.       */
__global__ void wconv_kernel(const float* __restrict__ W, bf16* __restrict__ Wt,
                             const float* __restrict__ cscale,
                             int K, int N, int Npad){
  __shared__ float tile[32][33];
  W  += (size_t)blockIdx.z*K*N;
  const float* cs = cscale ? (cscale + (size_t)blockIdx.z*K) : nullptr;
  Wt += (size_t)blockIdx.z*Npad*K;
  int kb = blockIdx.y*32, nb = blockIdx.x*32;
  int tx = threadIdx.x, ty = threadIdx.y;   /* 32 x 8 */
  #pragma unroll
  for (int r=0;r<32;r+=8){
    int k = kb+ty+r, n = nb+tx;
    float v = (k<K && n<N) ? W[(size_t)k*N+n] : 0.f;
    if (cs && k<K) v *= cs[k];
    tile[ty+r][tx] = v;
  }
  __syncthreads();
  #pragma unroll
  for (int r=0;r<32;r+=8){
    int n = nb+ty+r, k = kb+tx;
    if (n<Npad && k<K) Wt[(size_t)n*K+k] = __float2bfloat16(tile[tx][ty+r]);
  }
}

/* ---- x0 -> residual fragment blob (in d_out) ---------------------------------- */
__global__ __launch_bounds__(256) void xfrag_kernel(const float* __restrict__ x,
                                                    float* __restrict__ rf){
  const int tile = blockIdx.x*4 + (threadIdx.x>>6);   /* 12288 tiles */
  const int lane = threadIdx.x & 63;
  const int rt = tile/24, ct = tile%24;
  const int col = ct*16 + (lane&15);
  const int r0  = rt*16 + (lane>>4)*4;
  f32x4_t v;
  #pragma unroll
  for (int r=0;r<4;r++) v[r] = x[(size_t)(r0+r)*D_MODEL + col];
  *(f32x4_t*)(rf + RFT(rt,ct) + lane*4) = v;
}

/* ---------------- LayerNorm (layer 0 only): one WAVE per row of 384 -> bf16 ---- */
__global__ __launch_bounds__(256) void ln_kernel(const float* __restrict__ x, const float* __restrict__ w,
                          const float* __restrict__ b, unsigned short* __restrict__ o){
  const int wave = threadIdx.x >> 6, lane = threadIdx.x & 63;
  const int r = blockIdx.x*4 + wave;
  const float* xr = x + (size_t)r*D_MODEL;
  float2 v[3];
  float s = 0.f, sq = 0.f;
  #pragma unroll
  for (int e=0;e<3;e++){
    v[e] = *(const float2*)(xr + e*128 + lane*2);
    s  += v[e].x + v[e].y;
    sq += v[e].x*v[e].x + v[e].y*v[e].y;
  }
  #pragma unroll
  for (int off=1; off<64; off<<=1){
    s  += __shfl_xor(s, off);
    sq += __shfl_xor(sq, off);
  }
  float mu  = s*(1.f/D_MODEL);
  float var = sq*(1.f/D_MODEL) - mu*mu;
  var = var < 0.f ? 0.f : var;
  float rstd = rsqrtf(var + 1e-12f);
  unsigned short* orow = o + (size_t)r*D_MODEL;
  #pragma unroll
  for (int e=0;e<3;e++){
    int c = e*128 + lane*2;
    float2 wv = *(const float2*)(w + c);
    float2 bv = *(const float2*)(b + c);
    ushort2 ov;
    ov.x = f_to_bits((v[e].x-mu)*rstd*wv.x + bv.x);
    ov.y = f_to_bits((v[e].y-mu)*rstd*wv.y + bv.y);
    *(ushort2*)(orow + c) = ov;
  }
}

/* ------- bf16 MFMA GEMM (in-proj): 256x128 tile, BK=64, XOR-swizzled LDS -------
   448 blocks = one full round at 2 blocks/CU.                                 */
__global__ __launch_bounds__(256, 2) void gemm_in(
    const unsigned short* __restrict__ A,   /* M x 384 bf16, row-major */
    const unsigned short* __restrict__ Bt,  /* Npad x K bf16 (W_in transposed) */
    unsigned short* __restrict__ zfrag,     /* fragment blob, 48 col tiles */
    unsigned short* __restrict__ xbc,       /* M x XBC_LD bf16 */
    float* __restrict__ dtraw,              /* M x 8 fp32 */
    int K){
  __shared__ __align__(16) unsigned short smem[24576];  /* 48 KB: As 256x64 | Bs 128x64 */
  unsigned short* Bs = smem + 16384;
  const int tid = threadIdx.x;
  const int wave = tid >> 6, lane = tid & 63;
  const int lq = lane >> 4, lm = lane & 15;
  /* XCD swizzle: 448 blocks = 8 XCDs x 56 */
  const int lin = blockIdx.y*14 + blockIdx.x;
  const int nl  = (lin & 7)*56 + (lin >> 3);
  const int m0 = (nl / 14) * 256, n0 = (nl % 14) * 128;
  const int wm = (wave >> 1) * 128, wn = (wave & 1) * 64;
  f32x4_t acc[8][4];
  #pragma unroll
  for (int i=0;i<8;i++)
    #pragma unroll
    for (int j=0;j<4;j++)
      acc[i][j] = (f32x4_t){0.f,0.f,0.f,0.f};

  for (int k0 = 0; k0 < K; k0 += 64){
    if (k0) __syncthreads();
    #pragma unroll
    for (int q=0;q<8;q++){            /* A: 256 rows x 128 B */
      int o = q*4096 + wave*1024 + lane*16;
      int m = o >> 7;
      int kbs = (o & 127) ^ ((m & 7) << 4);
      const unsigned short* ga = A + (size_t)(m0+m)*K + k0 + (kbs>>1);
      __builtin_amdgcn_global_load_lds(
          (const __attribute__((address_space(1))) void*)ga,
          (__attribute__((address_space(3))) void*)((char*)smem + o), 16, 0, 0);
    }
    #pragma unroll
    for (int q=0;q<4;q++){            /* B: 128 rows x 128 B */
      int o = q*4096 + wave*1024 + lane*16;
      int n = o >> 7;
      int kbs = (o & 127) ^ ((n & 7) << 4);
      const unsigned short* gb = Bt + (size_t)(n0+n)*K + k0 + (kbs>>1);
      __builtin_amdgcn_global_load_lds(
          (const __attribute__((address_space(1))) void*)gb,
          (__attribute__((address_space(3))) void*)((char*)smem + 32768 + o), 16, 0, 0);
    }
    __syncthreads();
    #pragma unroll
    for (int kk=0;kk<2;kk++){
      bf16x8_t af[8], bfv[4];
      #pragma unroll
      for (int i=0;i<8;i++){
        int row = wm + i*16 + lm;
        int bo = (kk*64 + lq*16) ^ ((row & 7) << 4);
        af[i] = *(const bf16x8_t*)(smem + row*64 + (bo>>1));
      }
      #pragma unroll
      for (int j=0;j<4;j++){
        int row = wn + j*16 + lm;
        int bo = (kk*64 + lq*16) ^ ((row & 7) << 4);
        bfv[j] = *(const bf16x8_t*)(Bs + row*64 + (bo>>1));
      }
      #pragma unroll
      for (int i=0;i<8;i++)
        #pragma unroll
        for (int j=0;j<4;j++)
          acc[i][j] = __builtin_amdgcn_mfma_f32_16x16x32_bf16(af[i], bfv[j], acc[i][j], 0, 0, 0);
    }
  }

  if (n0 == 1664){
    /* dt block: local cols 0..7 are dt (fp32 direct); rest is padding */
    if ((wave & 1) == 0 && lm < 8){
      #pragma unroll
      for (int i=0;i<8;i++){
        int row = m0 + wm + i*16 + lq*4;
        #pragma unroll
        for (int r=0;r<4;r++)
          dtraw[(size_t)(row+r)*8 + lm] = acc[i][0][r];
      }
    }
    return;
  }
  if (n0 < 768){
    /* z tiles: direct fragment-blob stores, 8B/lane coalesced */
    #pragma unroll
    for (int i=0;i<8;i++){
      int rt = (m0 + wm + i*16) >> 4;
      #pragma unroll
      for (int j=0;j<4;j++){
        int ct = (n0 + wn + j*16) >> 4;
        ushort4 v4;
        v4.x = f_to_bits(acc[i][j][0]); v4.y = f_to_bits(acc[i][j][1]);
        v4.z = f_to_bits(acc[i][j][2]); v4.w = f_to_bits(acc[i][j][3]);
        *(ushort4*)(zfrag + ZFT(rt,ct) + lane*4) = v4;
      }
    }
    return;
  }
  /* xBC: row-major via LDS bounce, two 128-row half-passes */
  #pragma unroll
  for (int h=0;h<2;h++){
    __syncthreads();
    if ((wave >> 1) == h){
      #pragma unroll
      for (int i=0;i<8;i++){
        int rl = i*16 + lq*4;
        #pragma unroll
        for (int j=0;j<4;j++){
          int cl = wn + j*16 + lm;
          #pragma unroll
          for (int r=0;r<4;r++)
            smem[(rl+r)*136 + cl] = f_to_bits(acc[i][j][r]);
        }
      }
    }
    __syncthreads();
    int row = tid >> 1;
    int cbase = (tid & 1) * 64;
    size_t gb = (size_t)(m0 + h*128 + row) * XBC_LD + (n0 - 768) + cbase;
    #pragma unroll
    for (int k=0;k<8;k++)
      *(bf16x8_t*)(xbc + gb + k*8) = *(const bf16x8_t*)&smem[row*136 + cbase + k*8];
  }
}

/* ==== fused conv(k=4)+silu + dt/softplus + cumsum + chunked-SSD matmuls ========
   Conv is a SINGLE 35-step pass: waves 0-2 do X (1 col/thread, global reads);
   wave 3 does B and C together (dual rolling windows from LDS stage).         */
__global__ __launch_bounds__(256, 4) void fused_scan_kernel(
    const unsigned short* __restrict__ xbc, const float* __restrict__ dtraw,
    const float* __restrict__ cw, const float* __restrict__ cb,
    const float* __restrict__ dt_bias, const float* __restrict__ A_log,
    const float* __restrict__ D_skip,
    float* __restrict__ cumb, float* __restrict__ Dc,
    unsigned short* __restrict__ Cb, unsigned short* __restrict__ Sb,
    unsigned short* __restrict__ yfrag){
  __shared__ __align__(16) unsigned short Ssh[35*128];   /* B/C stage; Msh alias */
  __shared__ __align__(16) unsigned short XshT[192*40];  /* X^T[p_local][t] */
  __shared__ __align__(16) unsigned short BshT[64*40];   /* B^T[n][t] */
  __shared__ __align__(16) unsigned short Bsh[32*72];    /* B[t][n] */
  __shared__ __align__(16) unsigned short Csh[32*72];    /* C[t][n] */
  __shared__ float dtsh[64], Lsh[64], wsh[64];
  unsigned short* Msh = Ssh;                             /* 2*32*40 ushorts, post-conv */
  const int tid = threadIdx.x;
  const int bid = blockIdx.x;
  const int hp = bid & 3, c = (bid >> 2) & 31, b = bid >> 7;
  const int h_base = hp*2;
  const int t0 = c*CHUNK;

  /* ---- dt + raw log-decay for this block's 2 heads ---- */
  if (tid < 64){
    int hi = tid >> 5, t = tid & 31;
    int hg = h_base + hi;
    float raw = dtraw[(size_t)(b*SEQ + t0 + t)*8 + hg];
    float dtv_ = softplus_f(raw + dt_bias[hg]);
    dtsh[tid] = dtv_;
    Lsh[tid]  = dtv_ * (-expf(A_log[hg]));
  }

  /* ---- stage B/C conv input: 35 rows x 128 cols, 16B loads ---- */
  {
    const size_t rowbase = (size_t)b*SEQ*XBC_LD;
    for (int i = tid; i < 35*16; i += 256){
      int row = i/16, seg = i%16;
      int l = t0 - 3 + row;
      bf16x8_t v = {0,0,0,0,0,0,0,0};
      if (l >= 0)
        v = *(const bf16x8_t*)(xbc + rowbase + (size_t)l*XBC_LD + 768 + seg*8);
      *(bf16x8_t*)&Ssh[row*128 + seg*8] = v;
    }
  }
  __syncthreads();

  /* ---- conv: single pass. tids 0-191: X; tids 192-255: B and C (dual) ---- */
  if (tid < 192){
    int cch = h_base*96 + tid;
    float4 w4 = *(const float4*)(cw + cch*4);
    float bias = cb[cch];
    const unsigned short* src = xbc + (size_t)b*SEQ*XBC_LD + cch;  /* X: cch==gcol */
    float v0=0.f,v1=0.f,v2=0.f,v3=0.f;
    unsigned prev = 0;
    for (int t=-3; t<32; t++){
      int l = t0 + t;
      float nv = (l >= 0) ? bits_to_f(src[(size_t)l*XBC_LD]) : 0.f;
      v0=v1; v1=v2; v2=v3; v3=nv;
      if (t < 0) continue;
      float a = silu_f(bias + w4.x*v0 + w4.y*v1 + w4.z*v2 + w4.w*v3);
      unsigned short ub = f_to_bits(a);
      if (t & 1) *(unsigned*)&XshT[tid*40 + (t-1)] = prev | ((unsigned)ub<<16);
      else prev = ub;
    }
  } else {
    int n = tid - 192;                         /* 0..63 */
    int cchB = D_INNER + n, cchC = D_INNER + D_STATE + n;
    float4 wB = *(const float4*)(cw + cchB*4);
    float4 wC = *(const float4*)(cw + cchC*4);
    float bB = cb[cchB], bC = cb[cchC];
    float b0=0.f,b1=0.f,b2=0.f,b3=0.f;
    float c0=0.f,c1=0.f,c2=0.f,c3=0.f;
    unsigned prevB = 0;
    for (int t=-3; t<32; t++){
      float nb = bits_to_f(Ssh[(t+3)*128 + n]);
      float nc = bits_to_f(Ssh[(t+3)*128 + 64 + n]);
      b0=b1; b1=b2; b2=b3; b3=nb;
      c0=c1; c1=c2; c2=c3; c3=nc;
      if (t < 0) continue;
      float aB = silu_f(bB + wB.x*b0 + wB.y*b1 + wB.z*b2 + wB.w*b3);
      float aC = silu_f(bC + wC.x*c0 + wC.y*c1 + wC.z*c2 + wC.w*c3);
      unsigned short uB = f_to_bits(aB);
      Bsh[t*72 + n] = uB;
      Csh[t*72 + n] = f_to_bits(aC);
      if (t & 1) *(unsigned*)&BshT[n*40 + (t-1)] = prevB | ((unsigned)uB<<16);
      else prevB = uB;
    }
  }
  __syncthreads();

  /* ---- wave-parallel cumsum of log-decay (Hillis-Steele, 32-lane segments) ---- */
  if (tid < 64){
    int hg = h_base + (tid >> 5);
    float L = Lsh[tid];
    #pragma unroll
    for (int off=1; off<32; off<<=1){
      float nv = __shfl_up(L, off, 32);
      if ((tid & 31) >= off) L += nv;
    }
    Lsh[tid] = L;
    cumb[((size_t)((b*NC + c)*NHEADS) + hg)*CHUNK + (tid & 31)] = __expf(L);
    float Ltot = __shfl(L, 31, 32);
    if ((tid & 31) == 31) Dc[(b*NHEADS + hg)*NC + c] = __expf(L);
    wsh[tid] = __expf(Ltot - L) * dtsh[tid];
  }
  __syncthreads();

  const int wave = tid >> 6, lane = tid & 63;
  const int lq = lane >> 4, lm = lane & 15;
  const f32x4_t zero = (f32x4_t){0.f,0.f,0.f,0.f};

  /* ---- waves 0,1: G = C.B^T then M~ (D-skip on diagonal); waves 2,3: Cb out ---- */
  if (wave < 2){
    f32x4_t G[2][2];
    #pragma unroll
    for (int i=0;i<2;i++){ G[i][0]=zero; G[i][1]=zero; }
    #pragma unroll
    for (int kt=0; kt<2; kt++){
      bf16x8_t ca[2], bb[2];
      #pragma unroll
      for (int ti=0;ti<2;ti++)
        ca[ti] = *(const bf16x8_t*)&Csh[(lm+ti*16)*72 + kt*32 + lq*8];
      #pragma unroll
      for (int si=0;si<2;si++)
        bb[si] = *(const bf16x8_t*)&Bsh[(lm+si*16)*72 + kt*32 + lq*8];
      #pragma unroll
      for (int ti=0;ti<2;ti++)
        #pragma unroll
        for (int si=0;si<2;si++)
          G[ti][si] = __builtin_amdgcn_mfma_f32_16x16x32_bf16(ca[ti], bb[si], G[ti][si], 0,0,0);
    }
    int hi = wave;
    float Dk = D_skip[h_base + hi];
    float Lss[2], dts[2];
    #pragma unroll
    for (int si=0;si<2;si++){ Lss[si]=Lsh[hi*32+si*16+lm]; dts[si]=dtsh[hi*32+si*16+lm]; }
    #pragma unroll
    for (int ti=0;ti<2;ti++){
      #pragma unroll
      for (int r=0;r<4;r++){
        int t = ti*16 + lq*4 + r;
        float Lt = Lsh[hi*32 + t];
        #pragma unroll
        for (int si=0;si<2;si++){
          int s = si*16 + lm;
          float m = 0.f;
          if (s <= t){
            m = G[ti][si][r]*__expf(Lt - Lss[si])*dts[si];
            if (s == t) m += Dk;
          }
          Msh[hi*1280 + t*40 + s] = f_to_bits(m);
        }
      }
    }
  } else if (hp == 0){
    int lt = tid - 128;
    for (int i = lt; i < 512; i += 128){
      int t = i >> 4, q = i & 15;
      *(ushort4*)(Cb + ((size_t)(b*SEQ) + t0 + t)*D_STATE + q*4) =
          *(const ushort4*)&Csh[t*72 + q*4];
    }
  }
  __syncthreads();

  /* ---- compute: wave -> (head hi = wave&1, pt-half = wave>>1) ---- */
  {
    int hi = wave & 1, hg = h_base + hi;
    int ptb = (wave >> 1)*3;
    const int rt0 = (b*SEQ + t0) >> 4;
    bf16x8_t mf[2];
    #pragma unroll
    for (int tt=0;tt<2;tt++)
      mf[tt] = *(const bf16x8_t*)&Msh[hi*1280 + (lm+tt*16)*40 + lq*8];
    float wv[8];
    #pragma unroll
    for (int j=0;j<8;j++) wv[j] = wsh[hi*32 + lq*8 + j];
    bf16x8_t bw[4];
    #pragma unroll
    for (int nt=0;nt<4;nt++){
      bf16x8_t raw = *(const bf16x8_t*)&BshT[(lm+nt*16)*40 + lq*8];
      #pragma unroll
      for (int j=0;j<8;j++)
        bw[nt][j] = (short)f_to_bits(bits_to_f((unsigned short)raw[j]) * wv[j]);
    }
    const size_t sbase = ((size_t)((b*NC + c)*NHEADS) + hg)*HEADDIM*D_STATE;
    #pragma unroll
    for (int pp=0; pp<3; pp++){
      int pt = ptb + pp;
      bf16x8_t xf = *(const bf16x8_t*)&XshT[(hi*96 + pt*16 + lm)*40 + lq*8];
      /* Y1 (+ D*x via diagonal) -> fragment blob, 8B/lane */
      #pragma unroll
      for (int tt=0;tt<2;tt++){
        f32x4_t a = __builtin_amdgcn_mfma_f32_16x16x32_bf16(mf[tt], xf, zero, 0,0,0);
        ushort4 y4;
        y4.x = f_to_bits(a[0]); y4.y = f_to_bits(a[1]);
        y4.z = f_to_bits(a[2]); y4.w = f_to_bits(a[3]);
        *(ushort4*)(yfrag + ZFT(rt0+tt, hg*6+pt) + lane*4) = y4;
      }
      /* S = X^T @ (w.B) */
      #pragma unroll
      for (int nt=0;nt<4;nt++){
        f32x4_t s = __builtin_amdgcn_mfma_f32_16x16x32_bf16(xf, bw[nt], zero, 0,0,0);
        #pragma unroll
        for (int r=0;r<4;r++){
          int p = pt*16 + lq*4 + r;
          Sb[sbase + (size_t)p*D_STATE + nt*16 + lm] = f_to_bits(s[r]);
        }
      }
    }
  }
}

/* ---- sequential chunk combine on bf16 S (in-place -> Hin), 8-deep prefetch ----
   2 elems/thread -> 196608 threads (3 waves/SIMD TLP for the latency chain)  */
__global__ __launch_bounds__(256) void combine_kernel(
    unsigned short* __restrict__ S, const float* __restrict__ Dc){
  int g = blockIdx.x*256 + threadIdx.x;     /* (b,h,p,nq2): 8*8*96*32 = 196608 */
  int nq2 = g & 31;
  int p  = (g >> 5) % 96;
  int h  = (g / (32*96)) & 7;
  int b  = g / (32*96*8);
  const float* Dp = Dc + (size_t)(b*NHEADS + h)*NC;
  const size_t cstride = (size_t)NHEADS*HEADDIM*D_STATE;   /* 49152 */
  size_t base = (((size_t)(b*NC)*NHEADS + h)*HEADDIM + p)*D_STATE + nq2*2;
  float H0=0.f,H1=0.f;
  #pragma unroll 1
  for (int c=0;c<NC;c+=8){
    ushort2 s[8];
    #pragma unroll
    for (int q=0;q<8;q++)
      s[q] = *(ushort2*)(S + base + (size_t)q*cstride);
    #pragma unroll
    for (int q=0;q<8;q++){
      *(ushort2*)(S + base) = make_ushort2(f_to_bits(H0),f_to_bits(H1));
      float D = Dp[c+q];
      H0 = fmaf(D,H0,bits_to_f(s[q].x)); H1 = fmaf(D,H1,bits_to_f(s[q].y));
      base += cstride;
    }
  }
}

/* ==== fused tail: y+cum*(C@Hin^T), silu(z) gate, RMS (folded), @W_out into
   residual fragment blob, next-layer LN -> hnb. Last layer: row-major.
   Reductions use per-wave LDS slots (no atomics); cumb read direct.         == */
__global__ __launch_bounds__(1024, 4) void hinfuse_out_kernel(
    const unsigned short* __restrict__ Cb, const unsigned short* __restrict__ Hinb,
    const float* __restrict__ cumb, const unsigned short* __restrict__ zfrag,
    const unsigned short* __restrict__ yfrag,
    const unsigned short* __restrict__ Wot,   /* NPAD_OUT x D_INNER bf16 (norm_w-scaled) */
    float* __restrict__ outf,                 /* residual fragment blob / final out */
    const float* __restrict__ lnw, const float* __restrict__ lnb,
    unsigned short* __restrict__ hnb,         /* next-layer LN out, bf16 */
    int last){
  __shared__ __align__(16) unsigned short Vsh[32*VP];     /* 49664 B; f32 partial alias */
  __shared__ float rowsqW[16][32];
  __shared__ float rowsq[32];
  __shared__ float rsumW[8][32], rsqW[8][32], mu_s[32], rs_s[32];
  const int tid = threadIdx.x;
  const int c = blockIdx.x & 31, b = blockIdx.x >> 5;
  const int t0 = c*CHUNK;
  const int rt0 = (b*SEQ + t0) >> 4;
  const int wave = tid >> 6, lane = tid & 63;
  const int lq = lane >> 4, lm = lane & 15;
  const f32x4_t zero = (f32x4_t){0.f,0.f,0.f,0.f};

  /* ---- phase 1: V = (y + cum*C@Hin^T)*silu(z) -> Vsh; 2 waves/head (pt-halves) - */
  {
    float sql[2][4] = {};
    const int h = wave >> 1;
    const int pt0 = (wave & 1)*3;
    float cumv[2][4];
    {
      const float* cbp = cumb + ((size_t)((b*NC + c)*NHEADS) + h)*CHUNK;
      #pragma unroll
      for (int tt=0;tt<2;tt++)
        #pragma unroll
        for (int r=0;r<4;r++)
          cumv[tt][r] = cbp[tt*16 + lq*4 + r];
    }
    const unsigned short* Hb = Hinb + ((size_t)((b*NC + c)*NHEADS) + h)*HEADDIM*D_STATE;
    bf16x8_t ca[2][2];
    #pragma unroll
    for (int tt=0;tt<2;tt++)
      #pragma unroll
      for (int kt=0;kt<2;kt++)
        ca[tt][kt] = *(const bf16x8_t*)(Cb +
            ((size_t)(b*SEQ) + t0 + tt*16 + lm)*D_STATE + kt*32 + lq*8);
    #pragma unroll
    for (int pp=0; pp<3; pp++){
      int pt = pt0 + pp;
      bf16x8_t hf0 = *(const bf16x8_t*)&Hb[(size_t)(lm+pt*16)*D_STATE + lq*8];
      bf16x8_t hf1 = *(const bf16x8_t*)&Hb[(size_t)(lm+pt*16)*D_STATE + 32 + lq*8];
      f32x4_t acc[2];
      ushort4 yf4[2], zf4[2];
      #pragma unroll
      for (int tt=0;tt<2;tt++){
        yf4[tt] = *(const ushort4*)(yfrag + ZFT(rt0+tt, h*6+pt) + lane*4);
        zf4[tt] = *(const ushort4*)(zfrag + ZFT(rt0+tt, h*6+pt) + lane*4);
        acc[tt] = __builtin_amdgcn_mfma_f32_16x16x32_bf16(ca[tt][0], hf0, zero, 0,0,0);
        acc[tt] = __builtin_amdgcn_mfma_f32_16x16x32_bf16(ca[tt][1], hf1, acc[tt], 0,0,0);
      }
      int pcol = h*HEADDIM + pt*16 + lm;
      #pragma unroll
      for (int tt=0;tt<2;tt++){
        const unsigned short* yp = (const unsigned short*)&yf4[tt];
        const unsigned short* zp = (const unsigned short*)&zf4[tt];
        #pragma unroll
        for (int r=0;r<4;r++){
          int t = tt*16 + lq*4 + r;
          float yv = bits_to_f(yp[r]) + cumv[tt][r]*acc[tt][r];
          float z  = bits_to_f(zp[r]);
          float v  = yv * silu_f(z);
          Vsh[t*VP + pcol] = f_to_bits(v);
          sql[tt][r] += v*v;
        }
      }
    }
    /* per-wave slots: no atomics, no init */
    #pragma unroll
    for (int tt=0;tt<2;tt++)
      #pragma unroll
      for (int r=0;r<4;r++){
        float v = sql[tt][r];
        v += __shfl_xor(v,1); v += __shfl_xor(v,2);
        v += __shfl_xor(v,4); v += __shfl_xor(v,8);
        if (lm == 0) rowsqW[wave][tt*16 + lq*4 + r] = v;
      }
  }
  __syncthreads();
  if (tid < 32){
    float s = 0.f;
    #pragma unroll
    for (int w=0;w<16;w++) s += rowsqW[w][tid];
    rowsq[tid] = rsqrtf(s*(1.f/D_INNER) + 1e-5f);
  }
  __syncthreads();

  /* ---- phase 2: delta(32x384) = Vsh(32x768) @ Wot^T; 8 col-groups x 2 k-halves - */
  const int w8 = wave & 7, kh = wave >> 3;
  const int wn = w8*48;
  const int kbase = kh*384;
  f32x4_t acc[2][3];
  #pragma unroll
  for (int i=0;i<2;i++)
    #pragma unroll
    for (int j=0;j<3;j++)
      acc[i][j] = zero;
  {
    bf16x8_t afA[2], afB[2], bfA[3], bfB[3];
#define LOADK(af_, bf_, K0) { \
    af_[0] = *(const bf16x8_t*)&Vsh[(     lm)*VP + (K0) + lq*8]; \
    af_[1] = *(const bf16x8_t*)&Vsh[(16 + lm)*VP + (K0) + lq*8]; \
    bf_[0] = *(const bf16x8_t*)(Wot + (size_t)(wn      + lm)*D_INNER + (K0) + lq*8); \
    bf_[1] = *(const bf16x8_t*)(Wot + (size_t)(wn + 16 + lm)*D_INNER + (K0) + lq*8); \
    bf_[2] = *(const bf16x8_t*)(Wot + (size_t)(wn + 32 + lm)*D_INNER + (K0) + lq*8); \
  }
    LOADK(afA, bfA, kbase)
    #pragma unroll
    for (int ks=0; ks<12; ks+=2){
      LOADK(afB, bfB, kbase + (ks+1)*32)
      #pragma unroll
      for (int i=0;i<2;i++)
        #pragma unroll
        for (int j=0;j<3;j++)
          acc[i][j] = __builtin_amdgcn_mfma_f32_16x16x32_bf16(afA[i], bfA[j], acc[i][j], 0,0,0);
      if (ks+2 < 12) LOADK(afA, bfA, kbase + (ks+2)*32)
      #pragma unroll
      for (int i=0;i<2;i++)
        #pragma unroll
        for (int j=0;j<3;j++)
          acc[i][j] = __builtin_amdgcn_mfma_f32_16x16x32_bf16(afB[i], bfB[j], acc[i][j], 0,0,0);
    }
#undef LOADK
  }
  /* partial-sum reduce: kh=1 waves park partials in Vsh alias; kh=0 waves add */
  __syncthreads();                       /* all Vsh reads of phase 2 complete */
  {
    float* pr = (float*)Vsh;             /* 12288 floats = 48 KB */
    const int idx = (w8*64 + lane)*24;
    if (kh == 1){
      #pragma unroll
      for (int tt=0;tt<2;tt++)
        #pragma unroll
        for (int j=0;j<3;j++)
          #pragma unroll
          for (int r=0;r<4;r++)
            pr[idx + tt*12 + j*4 + r] = acc[tt][j][r];
    }
    __syncthreads();
    if (kh == 0){
      #pragma unroll
      for (int tt=0;tt<2;tt++)
        #pragma unroll
        for (int j=0;j<3;j++)
          #pragma unroll
          for (int r=0;r<4;r++)
            acc[tt][j][r] += pr[idx + tt*12 + j*4 + r];
    }
  }

  /* ---- phase 3 (waves kh==0): rms scale + residual RMW; LN -> hnb / row-major -- */
  float ov[2][3][4];
  if (kh == 0){
    #pragma unroll
    for (int tt=0;tt<2;tt++)
      #pragma unroll
      for (int j=0;j<3;j++){
        f32x4_t rv = *(const f32x4_t*)(outf + RFT(rt0+tt, w8*3+j) + lane*4);
        #pragma unroll
        for (int r=0;r<4;r++){
          float rms = rowsq[tt*16 + lq*4 + r];
          ov[tt][j][r] = rv[r] + acc[tt][j][r]*rms;
        }
      }
  }

  if (last){
    __syncthreads();   /* all fragment reads done before row-major writes to slab */
    if (kh == 0){
      #pragma unroll
      for (int tt=0;tt<2;tt++)
        #pragma unroll
        for (int r=0;r<4;r++){
          size_t row = (size_t)(b*SEQ) + t0 + tt*16 + lq*4 + r;
          #pragma unroll
          for (int j=0;j<3;j++)
            outf[row*D_MODEL + wn + j*16 + lm] = ov[tt][j][r];
        }
    }
    return;
  }

  if (kh == 0){
    #pragma unroll
    for (int tt=0;tt<2;tt++)
      #pragma unroll
      for (int j=0;j<3;j++){
        f32x4_t rv;
        #pragma unroll
        for (int r=0;r<4;r++) rv[r] = ov[tt][j][r];
        *(f32x4_t*)(outf + RFT(rt0+tt, w8*3+j) + lane*4) = rv;
      }
    /* LN stats into per-wave slots (no atomics) */
    #pragma unroll
    for (int tt=0;tt<2;tt++){
      #pragma unroll
      for (int r=0;r<4;r++){
        int t = tt*16 + lq*4 + r;
        float s = 0.f, sq = 0.f;
        #pragma unroll
        for (int j=0;j<3;j++){ float o = ov[tt][j][r]; s += o; sq += o*o; }
        s  += __shfl_xor(s,1);  s  += __shfl_xor(s,2);  s  += __shfl_xor(s,4);  s  += __shfl_xor(s,8);
        sq += __shfl_xor(sq,1); sq += __shfl_xor(sq,2); sq += __shfl_xor(sq,4); sq += __shfl_xor(sq,8);
        if (lm == 0){ rsumW[w8][t] = s; rsqW[w8][t] = sq; }
      }
    }
  }
  __syncthreads();
  if (tid < 32){
    float s = 0.f, sq = 0.f;
    #pragma unroll
    for (int w=0;w<8;w++){ s += rsumW[w][tid]; sq += rsqW[w][tid]; }
    float mu  = s*(1.f/D_MODEL);
    float var = sq*(1.f/D_MODEL) - mu*mu;
    var = var < 0.f ? 0.f : var;
    mu_s[tid] = mu;
    rs_s[tid] = rsqrtf(var + 1e-12f);
  }
  __syncthreads();
  if (kh == 0){
    #pragma unroll
    for (int tt=0;tt<2;tt++){
      #pragma unroll
      for (int r=0;r<4;r++){
        int t = tt*16 + lq*4 + r;
        size_t row = (size_t)(b*SEQ) + t0 + t;
        float mu = mu_s[t], rs = rs_s[t];
        #pragma unroll
        for (int j=0;j<3;j++){
          int n = wn + j*16 + lm;
          hnb[row*D_MODEL + n] = f_to_bits((ov[tt][j][r]-mu)*rs*lnw[n] + lnb[n]);
        }
      }
    }
  }
}

extern "C" void kernel_launch(void* const* d_in, const int* in_sizes, int n_in,
                              void* d_out, int out_size, void* d_ws, size_t ws_size,
                              hipStream_t stream){
  const float* x0      = (const float*)d_in[0];
  const float* ln_w    = (const float*)d_in[1];
  const float* ln_b    = (const float*)d_in[2];
  const float* W_in    = (const float*)d_in[3];
  const float* conv_w  = (const float*)d_in[4];
  const float* conv_b  = (const float*)d_in[5];
  const float* dt_bias = (const float*)d_in[6];
  const float* A_log   = (const float*)d_in[7];
  const float* D_skip  = (const float*)d_in[8];
  const float* norm_w  = (const float*)d_in[9];
  const float* W_out   = (const float*)d_in[10];
  float* out = (float*)d_out;

  /* workspace (float units), ~85 MB */
  float* p    = (float*)d_ws;
  unsigned short* xbc   = (unsigned short*)p; p += (size_t)ROWS*XBC_LD/2;
  float* dtraw = p;  p += (size_t)ROWS*8;
  float* cumb  = p;  p += (size_t)BATCH*NHEADS*SEQ;
  float* Dc    = p;  p += (size_t)BATCH*NHEADS*NC;
  unsigned short* yfrag = (unsigned short*)p; p += (size_t)ROWS*D_INNER/2;
  unsigned short* zfrag = (unsigned short*)p; p += (size_t)ROWS*D_INNER/2;
  unsigned short* hnb   = (unsigned short*)p; p += (size_t)ROWS*D_MODEL/2;
  unsigned short* Sb    = (unsigned short*)p; p += (size_t)BATCH*NC*NHEADS*HEADDIM*D_STATE/2;
  unsigned short* Cb    = (unsigned short*)p; p += (size_t)ROWS*D_STATE/2;
  bf16* Wt  = (bf16*)p; p += (size_t)NUM_LAYERS*NPAD_IN*D_MODEL/2;
  bf16* Wot = (bf16*)p;

  wconv_kernel<<<dim3(NPAD_IN/32, D_MODEL/32, NUM_LAYERS), dim3(32,8), 0, stream>>>(
      W_in, Wt, nullptr, D_MODEL, D_IN_PROJ, NPAD_IN);
  /* fold norm_w into W_out rows (k = D_INNER dim) */
  wconv_kernel<<<dim3(NPAD_OUT/32, D_INNER/32, NUM_LAYERS), dim3(32,8), 0, stream>>>(
      W_out, Wot, norm_w, D_INNER, D_MODEL, NPAD_OUT);

  /* residual stream -> fragment blob inside d_out; layer-0 LN from x0 */
  xfrag_kernel<<<(ROWS/16)*24/4, 256, 0, stream>>>(x0, out);
  ln_kernel<<<ROWS/4,256,0,stream>>>(x0, ln_w, ln_b, hnb);

  for (int i=0;i<NUM_LAYERS;i++){
    int last = (i == NUM_LAYERS-1);
    gemm_in<<<dim3(14, ROWS/256), 256, 0, stream>>>(
        (const unsigned short*)hnb, (const unsigned short*)(Wt + (size_t)i*NPAD_IN*D_MODEL),
        zfrag, xbc, dtraw, D_MODEL);
    fused_scan_kernel<<<BATCH*NC*4, 256, 0, stream>>>(
        xbc, dtraw, conv_w + (size_t)i*CONV_DIM*4, conv_b + (size_t)i*CONV_DIM,
        dt_bias+(size_t)i*NHEADS, A_log+(size_t)i*NHEADS, D_skip+(size_t)i*NHEADS,
        cumb, Dc, Cb, Sb, yfrag);
    combine_kernel<<<(BATCH*NHEADS*HEADDIM*32)/256, 256, 0, stream>>>(Sb, Dc);
    hinfuse_out_kernel<<<BATCH*NC, 1024, 0, stream>>>(
        Cb, Sb, cumb, zfrag, yfrag,
        (const unsigned short*)(Wot + (size_t)i*NPAD_OUT*D_INNER), out,
        ln_w + (size_t)(last ? i : i+1)*D_MODEL,
        ln_b + (size_t)(last ? i : i+1)*D_MODEL,
        hnb, last);
  }
}

// Round 16
// 619.605 us; speedup vs baseline: 1.1442x; 1.0076x over previous
//
#include <hip/hip_runtime.h>
#include <hip/hip_bf16.h>
#include <math.h>

#define D_MODEL 384
#define D_STATE 64
#define D_INNER 768
#define HEADDIM 96
#define NHEADS 8
#define CONV_DIM 896
#define D_IN_PROJ 1672
#define XBC_LD 896         /* bf16 xBC row stride (X 0..767, B 768..831, C 832..895) */
#define BATCH 8
#define SEQ 1024
#define ROWS (BATCH*SEQ)   /* 8192 */
#define NUM_LAYERS 6
#define NC 32              /* chunks */
#define CHUNK 32           /* timesteps per chunk */
#define NPAD_IN 1792       /* 14 * 128 */
#define NPAD_OUT 384       /* 3 * 128  */
#define VP 776             /* padded Vsh row (shorts) */

/* fragment-tile layout: 16x16 tile stored as 256 elems, lane*4 + r
   (col = lane&15, row = (lane>>4)*4 + r)  -- matches MFMA C-layout      */
#define ZFT(rt,ct) (((size_t)(rt)*48 + (ct))*256)   /* 768-col blobs (z,y) */
#define RFT(rt,ct) (((size_t)(rt)*24 + (ct))*256)   /* 384-col blob (residual) */

typedef __hip_bfloat16 bf16;
using bf16x8_t = __attribute__((ext_vector_type(8))) short;
using f32x4_t  = __attribute__((ext_vector_type(4))) float;

__device__ __forceinline__ float softplus_f(float v){
  return v > 20.f ? v : log1pf(expf(v));
}
__device__ __forceinline__ float silu_f(float v){
  return v / (1.f + expf(-v));
}
__device__ __forceinline__ float bits_to_f(unsigned short u){
  union{unsigned u32; float f;} cv; cv.u32 = ((unsigned)u)<<16; return cv.f;
}
__device__ __forceinline__ unsigned short f_to_bits(float f){
  union{bf16 b; unsigned short u;} cv; cv.b = __float2bfloat16(f); return cv.u;
}

/* ------- weight transpose + fp32->bf16, all layers batched via grid.z ----------
   cscale (optional, per-layer stride K): fold norm_w into W_out columns.       */
__global__ void wconv_kernel(const float* __restrict__ W, bf16* __restrict__ Wt,
                             const float* __restrict__ cscale,
                             int K, int N, int Npad){
  __shared__ float tile[32][33];
  W  += (size_t)blockIdx.z*K*N;
  const float* cs = cscale ? (cscale + (size_t)blockIdx.z*K) : nullptr;
  Wt += (size_t)blockIdx.z*Npad*K;
  int kb = blockIdx.y*32, nb = blockIdx.x*32;
  int tx = threadIdx.x, ty = threadIdx.y;   /* 32 x 8 */
  #pragma unroll
  for (int r=0;r<32;r+=8){
    int k = kb+ty+r, n = nb+tx;
    float v = (k<K && n<N) ? W[(size_t)k*N+n] : 0.f;
    if (cs && k<K) v *= cs[k];
    tile[ty+r][tx] = v;
  }
  __syncthreads();
  #pragma unroll
  for (int r=0;r<32;r+=8){
    int n = nb+ty+r, k = kb+tx;
    if (n<Npad && k<K) Wt[(size_t)n*K+k] = __float2bfloat16(tile[tx][ty+r]);
  }
}

/* ---- x0 -> residual fragment blob (in d_out) ---------------------------------- */
__global__ __launch_bounds__(256) void xfrag_kernel(const float* __restrict__ x,
                                                    float* __restrict__ rf){
  const int tile = blockIdx.x*4 + (threadIdx.x>>6);   /* 12288 tiles */
  const int lane = threadIdx.x & 63;
  const int rt = tile/24, ct = tile%24;
  const int col = ct*16 + (lane&15);
  const int r0  = rt*16 + (lane>>4)*4;
  f32x4_t v;
  #pragma unroll
  for (int r=0;r<4;r++) v[r] = x[(size_t)(r0+r)*D_MODEL + col];
  *(f32x4_t*)(rf + RFT(rt,ct) + lane*4) = v;
}

/* ---------------- LayerNorm (layer 0 only): one WAVE per row of 384 -> bf16 ---- */
__global__ __launch_bounds__(256) void ln_kernel(const float* __restrict__ x, const float* __restrict__ w,
                          const float* __restrict__ b, unsigned short* __restrict__ o){
  const int wave = threadIdx.x >> 6, lane = threadIdx.x & 63;
  const int r = blockIdx.x*4 + wave;
  const float* xr = x + (size_t)r*D_MODEL;
  float2 v[3];
  float s = 0.f, sq = 0.f;
  #pragma unroll
  for (int e=0;e<3;e++){
    v[e] = *(const float2*)(xr + e*128 + lane*2);
    s  += v[e].x + v[e].y;
    sq += v[e].x*v[e].x + v[e].y*v[e].y;
  }
  #pragma unroll
  for (int off=1; off<64; off<<=1){
    s  += __shfl_xor(s, off);
    sq += __shfl_xor(sq, off);
  }
  float mu  = s*(1.f/D_MODEL);
  float var = sq*(1.f/D_MODEL) - mu*mu;
  var = var < 0.f ? 0.f : var;
  float rstd = rsqrtf(var + 1e-12f);
  unsigned short* orow = o + (size_t)r*D_MODEL;
  #pragma unroll
  for (int e=0;e<3;e++){
    int c = e*128 + lane*2;
    float2 wv = *(const float2*)(w + c);
    float2 bv = *(const float2*)(b + c);
    ushort2 ov;
    ov.x = f_to_bits((v[e].x-mu)*rstd*wv.x + bv.x);
    ov.y = f_to_bits((v[e].y-mu)*rstd*wv.y + bv.y);
    *(ushort2*)(orow + c) = ov;
  }
}

/* ------- bf16 MFMA GEMM (in-proj): 256x128 tile, BK=64, XOR-swizzled LDS -------
   448 blocks = one full round at 2 blocks/CU.                                 */
__global__ __launch_bounds__(256, 2) void gemm_in(
    const unsigned short* __restrict__ A,   /* M x 384 bf16, row-major */
    const unsigned short* __restrict__ Bt,  /* Npad x K bf16 (W_in transposed) */
    unsigned short* __restrict__ zfrag,     /* fragment blob, 48 col tiles */
    unsigned short* __restrict__ xbc,       /* M x XBC_LD bf16 */
    float* __restrict__ dtraw,              /* M x 8 fp32 */
    int K){
  __shared__ __align__(16) unsigned short smem[24576];  /* 48 KB: As 256x64 | Bs 128x64 */
  unsigned short* Bs = smem + 16384;
  const int tid = threadIdx.x;
  const int wave = tid >> 6, lane = tid & 63;
  const int lq = lane >> 4, lm = lane & 15;
  /* XCD swizzle: 448 blocks = 8 XCDs x 56 */
  const int lin = blockIdx.y*14 + blockIdx.x;
  const int nl  = (lin & 7)*56 + (lin >> 3);
  const int m0 = (nl / 14) * 256, n0 = (nl % 14) * 128;
  const int wm = (wave >> 1) * 128, wn = (wave & 1) * 64;
  f32x4_t acc[8][4];
  #pragma unroll
  for (int i=0;i<8;i++)
    #pragma unroll
    for (int j=0;j<4;j++)
      acc[i][j] = (f32x4_t){0.f,0.f,0.f,0.f};

  for (int k0 = 0; k0 < K; k0 += 64){
    if (k0) __syncthreads();
    #pragma unroll
    for (int q=0;q<8;q++){            /* A: 256 rows x 128 B */
      int o = q*4096 + wave*1024 + lane*16;
      int m = o >> 7;
      int kbs = (o & 127) ^ ((m & 7) << 4);
      const unsigned short* ga = A + (size_t)(m0+m)*K + k0 + (kbs>>1);
      __builtin_amdgcn_global_load_lds(
          (const __attribute__((address_space(1))) void*)ga,
          (__attribute__((address_space(3))) void*)((char*)smem + o), 16, 0, 0);
    }
    #pragma unroll
    for (int q=0;q<4;q++){            /* B: 128 rows x 128 B */
      int o = q*4096 + wave*1024 + lane*16;
      int n = o >> 7;
      int kbs = (o & 127) ^ ((n & 7) << 4);
      const unsigned short* gb = Bt + (size_t)(n0+n)*K + k0 + (kbs>>1);
      __builtin_amdgcn_global_load_lds(
          (const __attribute__((address_space(1))) void*)gb,
          (__attribute__((address_space(3))) void*)((char*)smem + 32768 + o), 16, 0, 0);
    }
    __syncthreads();
    #pragma unroll
    for (int kk=0;kk<2;kk++){
      bf16x8_t af[8], bfv[4];
      #pragma unroll
      for (int i=0;i<8;i++){
        int row = wm + i*16 + lm;
        int bo = (kk*64 + lq*16) ^ ((row & 7) << 4);
        af[i] = *(const bf16x8_t*)(smem + row*64 + (bo>>1));
      }
      #pragma unroll
      for (int j=0;j<4;j++){
        int row = wn + j*16 + lm;
        int bo = (kk*64 + lq*16) ^ ((row & 7) << 4);
        bfv[j] = *(const bf16x8_t*)(Bs + row*64 + (bo>>1));
      }
      #pragma unroll
      for (int i=0;i<8;i++)
        #pragma unroll
        for (int j=0;j<4;j++)
          acc[i][j] = __builtin_amdgcn_mfma_f32_16x16x32_bf16(af[i], bfv[j], acc[i][j], 0, 0, 0);
    }
  }

  if (n0 == 1664){
    /* dt block: local cols 0..7 are dt (fp32 direct); rest is padding */
    if ((wave & 1) == 0 && lm < 8){
      #pragma unroll
      for (int i=0;i<8;i++){
        int row = m0 + wm + i*16 + lq*4;
        #pragma unroll
        for (int r=0;r<4;r++)
          dtraw[(size_t)(row+r)*8 + lm] = acc[i][0][r];
      }
    }
    return;
  }
  if (n0 < 768){
    /* z tiles: direct fragment-blob stores, 8B/lane coalesced */
    #pragma unroll
    for (int i=0;i<8;i++){
      int rt = (m0 + wm + i*16) >> 4;
      #pragma unroll
      for (int j=0;j<4;j++){
        int ct = (n0 + wn + j*16) >> 4;
        ushort4 v4;
        v4.x = f_to_bits(acc[i][j][0]); v4.y = f_to_bits(acc[i][j][1]);
        v4.z = f_to_bits(acc[i][j][2]); v4.w = f_to_bits(acc[i][j][3]);
        *(ushort4*)(zfrag + ZFT(rt,ct) + lane*4) = v4;
      }
    }
    return;
  }
  /* xBC: row-major via LDS bounce, two 128-row half-passes */
  #pragma unroll
  for (int h=0;h<2;h++){
    __syncthreads();
    if ((wave >> 1) == h){
      #pragma unroll
      for (int i=0;i<8;i++){
        int rl = i*16 + lq*4;
        #pragma unroll
        for (int j=0;j<4;j++){
          int cl = wn + j*16 + lm;
          #pragma unroll
          for (int r=0;r<4;r++)
            smem[(rl+r)*136 + cl] = f_to_bits(acc[i][j][r]);
        }
      }
    }
    __syncthreads();
    int row = tid >> 1;
    int cbase = (tid & 1) * 64;
    size_t gb = (size_t)(m0 + h*128 + row) * XBC_LD + (n0 - 768) + cbase;
    #pragma unroll
    for (int k=0;k<8;k++)
      *(bf16x8_t*)(xbc + gb + k*8) = *(const bf16x8_t*)&smem[row*136 + cbase + k*8];
  }
}

/* ==== fused conv(k=4)+silu + dt/softplus + cumsum + chunked-SSD matmuls ========
   Conv is a SINGLE 35-step pass; X path hoists all 35 loads into registers
   (burst-issued) before the silu window loop. Wave 3 does B and C (dual).     */
__global__ __launch_bounds__(256, 4) void fused_scan_kernel(
    const unsigned short* __restrict__ xbc, const float* __restrict__ dtraw,
    const float* __restrict__ cw, const float* __restrict__ cb,
    const float* __restrict__ dt_bias, const float* __restrict__ A_log,
    const float* __restrict__ D_skip,
    float* __restrict__ cumb, float* __restrict__ Dc,
    unsigned short* __restrict__ Cb, unsigned short* __restrict__ Sb,
    unsigned short* __restrict__ yfrag){
  __shared__ __align__(16) unsigned short Ssh[35*128];   /* B/C stage; Msh alias */
  __shared__ __align__(16) unsigned short XshT[192*40];  /* X^T[p_local][t] */
  __shared__ __align__(16) unsigned short BshT[64*40];   /* B^T[n][t] */
  __shared__ __align__(16) unsigned short Bsh[32*72];    /* B[t][n] */
  __shared__ __align__(16) unsigned short Csh[32*72];    /* C[t][n] */
  __shared__ float dtsh[64], Lsh[64], wsh[64];
  unsigned short* Msh = Ssh;                             /* 2*32*40 ushorts, post-conv */
  const int tid = threadIdx.x;
  const int bid = blockIdx.x;
  const int hp = bid & 3, c = (bid >> 2) & 31, b = bid >> 7;
  const int h_base = hp*2;
  const int t0 = c*CHUNK;

  /* ---- dt + raw log-decay for this block's 2 heads ---- */
  if (tid < 64){
    int hi = tid >> 5, t = tid & 31;
    int hg = h_base + hi;
    float raw = dtraw[(size_t)(b*SEQ + t0 + t)*8 + hg];
    float dtv_ = softplus_f(raw + dt_bias[hg]);
    dtsh[tid] = dtv_;
    Lsh[tid]  = dtv_ * (-expf(A_log[hg]));
  }

  /* ---- stage B/C conv input: 35 rows x 128 cols, 16B loads ---- */
  {
    const size_t rowbase = (size_t)b*SEQ*XBC_LD;
    for (int i = tid; i < 35*16; i += 256){
      int row = i/16, seg = i%16;
      int l = t0 - 3 + row;
      bf16x8_t v = {0,0,0,0,0,0,0,0};
      if (l >= 0)
        v = *(const bf16x8_t*)(xbc + rowbase + (size_t)l*XBC_LD + 768 + seg*8);
      *(bf16x8_t*)&Ssh[row*128 + seg*8] = v;
    }
  }
  __syncthreads();

  /* ---- conv: single pass. tids 0-191: X (reg-hoisted); 192-255: B+C (dual) ---- */
  if (tid < 192){
    int cch = h_base*96 + tid;
    float4 w4 = *(const float4*)(cw + cch*4);
    float bias = cb[cch];
    const unsigned short* src = xbc + (size_t)b*SEQ*XBC_LD + cch;  /* X: cch==gcol */
    float xv[35];
    #pragma unroll
    for (int i=0;i<35;i++){
      int l = t0 - 3 + i;
      xv[i] = (l >= 0) ? bits_to_f(src[(size_t)l*XBC_LD]) : 0.f;
    }
    unsigned prev = 0;
    #pragma unroll
    for (int t=0; t<32; t++){
      float a = silu_f(bias + w4.x*xv[t] + w4.y*xv[t+1] + w4.z*xv[t+2] + w4.w*xv[t+3]);
      unsigned short ub = f_to_bits(a);
      if (t & 1) *(unsigned*)&XshT[tid*40 + (t-1)] = prev | ((unsigned)ub<<16);
      else prev = ub;
    }
  } else {
    int n = tid - 192;                         /* 0..63 */
    int cchB = D_INNER + n, cchC = D_INNER + D_STATE + n;
    float4 wB = *(const float4*)(cw + cchB*4);
    float4 wC = *(const float4*)(cw + cchC*4);
    float bB = cb[cchB], bC = cb[cchC];
    float b0=0.f,b1=0.f,b2=0.f,b3=0.f;
    float c0=0.f,c1=0.f,c2=0.f,c3=0.f;
    unsigned prevB = 0;
    for (int t=-3; t<32; t++){
      float nb = bits_to_f(Ssh[(t+3)*128 + n]);
      float nc = bits_to_f(Ssh[(t+3)*128 + 64 + n]);
      b0=b1; b1=b2; b2=b3; b3=nb;
      c0=c1; c1=c2; c2=c3; c3=nc;
      if (t < 0) continue;
      float aB = silu_f(bB + wB.x*b0 + wB.y*b1 + wB.z*b2 + wB.w*b3);
      float aC = silu_f(bC + wC.x*c0 + wC.y*c1 + wC.z*c2 + wC.w*c3);
      unsigned short uB = f_to_bits(aB);
      Bsh[t*72 + n] = uB;
      Csh[t*72 + n] = f_to_bits(aC);
      if (t & 1) *(unsigned*)&BshT[n*40 + (t-1)] = prevB | ((unsigned)uB<<16);
      else prevB = uB;
    }
  }
  __syncthreads();

  /* ---- wave-parallel cumsum of log-decay (Hillis-Steele, 32-lane segments) ---- */
  if (tid < 64){
    int hg = h_base + (tid >> 5);
    float L = Lsh[tid];
    #pragma unroll
    for (int off=1; off<32; off<<=1){
      float nv = __shfl_up(L, off, 32);
      if ((tid & 31) >= off) L += nv;
    }
    Lsh[tid] = L;
    cumb[((size_t)((b*NC + c)*NHEADS) + hg)*CHUNK + (tid & 31)] = __expf(L);
    float Ltot = __shfl(L, 31, 32);
    if ((tid & 31) == 31) Dc[(b*NHEADS + hg)*NC + c] = __expf(L);
    wsh[tid] = __expf(Ltot - L) * dtsh[tid];
  }
  __syncthreads();

  const int wave = tid >> 6, lane = tid & 63;
  const int lq = lane >> 4, lm = lane & 15;
  const f32x4_t zero = (f32x4_t){0.f,0.f,0.f,0.f};

  /* ---- waves 0,1: G = C.B^T then M~ (D-skip on diagonal); waves 2,3: Cb out ---- */
  if (wave < 2){
    f32x4_t G[2][2];
    #pragma unroll
    for (int i=0;i<2;i++){ G[i][0]=zero; G[i][1]=zero; }
    #pragma unroll
    for (int kt=0; kt<2; kt++){
      bf16x8_t ca[2], bb[2];
      #pragma unroll
      for (int ti=0;ti<2;ti++)
        ca[ti] = *(const bf16x8_t*)&Csh[(lm+ti*16)*72 + kt*32 + lq*8];
      #pragma unroll
      for (int si=0;si<2;si++)
        bb[si] = *(const bf16x8_t*)&Bsh[(lm+si*16)*72 + kt*32 + lq*8];
      #pragma unroll
      for (int ti=0;ti<2;ti++)
        #pragma unroll
        for (int si=0;si<2;si++)
          G[ti][si] = __builtin_amdgcn_mfma_f32_16x16x32_bf16(ca[ti], bb[si], G[ti][si], 0,0,0);
    }
    int hi = wave;
    float Dk = D_skip[h_base + hi];
    float Lss[2], dts[2];
    #pragma unroll
    for (int si=0;si<2;si++){ Lss[si]=Lsh[hi*32+si*16+lm]; dts[si]=dtsh[hi*32+si*16+lm]; }
    #pragma unroll
    for (int ti=0;ti<2;ti++){
      #pragma unroll
      for (int r=0;r<4;r++){
        int t = ti*16 + lq*4 + r;
        float Lt = Lsh[hi*32 + t];
        #pragma unroll
        for (int si=0;si<2;si++){
          int s = si*16 + lm;
          float m = 0.f;
          if (s <= t){
            m = G[ti][si][r]*__expf(Lt - Lss[si])*dts[si];
            if (s == t) m += Dk;
          }
          Msh[hi*1280 + t*40 + s] = f_to_bits(m);
        }
      }
    }
  } else if (hp == 0){
    int lt = tid - 128;
    for (int i = lt; i < 512; i += 128){
      int t = i >> 4, q = i & 15;
      *(ushort4*)(Cb + ((size_t)(b*SEQ) + t0 + t)*D_STATE + q*4) =
          *(const ushort4*)&Csh[t*72 + q*4];
    }
  }
  __syncthreads();

  /* ---- compute: wave -> (head hi = wave&1, pt-half = wave>>1) ---- */
  {
    int hi = wave & 1, hg = h_base + hi;
    int ptb = (wave >> 1)*3;
    const int rt0 = (b*SEQ + t0) >> 4;
    bf16x8_t mf[2];
    #pragma unroll
    for (int tt=0;tt<2;tt++)
      mf[tt] = *(const bf16x8_t*)&Msh[hi*1280 + (lm+tt*16)*40 + lq*8];
    float wv[8];
    #pragma unroll
    for (int j=0;j<8;j++) wv[j] = wsh[hi*32 + lq*8 + j];
    bf16x8_t bw[4];
    #pragma unroll
    for (int nt=0;nt<4;nt++){
      bf16x8_t raw = *(const bf16x8_t*)&BshT[(lm+nt*16)*40 + lq*8];
      #pragma unroll
      for (int j=0;j<8;j++)
        bw[nt][j] = (short)f_to_bits(bits_to_f((unsigned short)raw[j]) * wv[j]);
    }
    const size_t sbase = ((size_t)((b*NC + c)*NHEADS) + hg)*HEADDIM*D_STATE;
    #pragma unroll
    for (int pp=0; pp<3; pp++){
      int pt = ptb + pp;
      bf16x8_t xf = *(const bf16x8_t*)&XshT[(hi*96 + pt*16 + lm)*40 + lq*8];
      /* Y1 (+ D*x via diagonal) -> fragment blob, 8B/lane */
      #pragma unroll
      for (int tt=0;tt<2;tt++){
        f32x4_t a = __builtin_amdgcn_mfma_f32_16x16x32_bf16(mf[tt], xf, zero, 0,0,0);
        ushort4 y4;
        y4.x = f_to_bits(a[0]); y4.y = f_to_bits(a[1]);
        y4.z = f_to_bits(a[2]); y4.w = f_to_bits(a[3]);
        *(ushort4*)(yfrag + ZFT(rt0+tt, hg*6+pt) + lane*4) = y4;
      }
      /* S = X^T @ (w.B) */
      #pragma unroll
      for (int nt=0;nt<4;nt++){
        f32x4_t s = __builtin_amdgcn_mfma_f32_16x16x32_bf16(xf, bw[nt], zero, 0,0,0);
        #pragma unroll
        for (int r=0;r<4;r++){
          int p = pt*16 + lq*4 + r;
          Sb[sbase + (size_t)p*D_STATE + nt*16 + lm] = f_to_bits(s[r]);
        }
      }
    }
  }
}

/* ---- sequential chunk combine on bf16 S (in-place -> Hin), 8-deep prefetch ----
   2 elems/thread -> 196608 threads (3 waves/SIMD TLP for the latency chain)  */
__global__ __launch_bounds__(256) void combine_kernel(
    unsigned short* __restrict__ S, const float* __restrict__ Dc){
  int g = blockIdx.x*256 + threadIdx.x;     /* (b,h,p,nq2): 8*8*96*32 = 196608 */
  int nq2 = g & 31;
  int p  = (g >> 5) % 96;
  int h  = (g / (32*96)) & 7;
  int b  = g / (32*96*8);
  const float* Dp = Dc + (size_t)(b*NHEADS + h)*NC;
  const size_t cstride = (size_t)NHEADS*HEADDIM*D_STATE;   /* 49152 */
  size_t base = (((size_t)(b*NC)*NHEADS + h)*HEADDIM + p)*D_STATE + nq2*2;
  float H0=0.f,H1=0.f;
  #pragma unroll 1
  for (int c=0;c<NC;c+=8){
    ushort2 s[8];
    #pragma unroll
    for (int q=0;q<8;q++)
      s[q] = *(ushort2*)(S + base + (size_t)q*cstride);
    #pragma unroll
    for (int q=0;q<8;q++){
      *(ushort2*)(S + base) = make_ushort2(f_to_bits(H0),f_to_bits(H1));
      float D = Dp[c+q];
      H0 = fmaf(D,H0,bits_to_f(s[q].x)); H1 = fmaf(D,H1,bits_to_f(s[q].y));
      base += cstride;
    }
  }
}

/* ==== fused tail: y+cum*(C@Hin^T), silu(z) gate, RMS (folded), @W_out into
   residual fragment blob, next-layer LN -> hnb. Last layer: row-major.
   Phase-1 loads (Hb/yfrag/zfrag) hoisted before the compute loop.           == */
__global__ __launch_bounds__(1024, 4) void hinfuse_out_kernel(
    const unsigned short* __restrict__ Cb, const unsigned short* __restrict__ Hinb,
    const float* __restrict__ cumb, const unsigned short* __restrict__ zfrag,
    const unsigned short* __restrict__ yfrag,
    const unsigned short* __restrict__ Wot,   /* NPAD_OUT x D_INNER bf16 (norm_w-scaled) */
    float* __restrict__ outf,                 /* residual fragment blob / final out */
    const float* __restrict__ lnw, const float* __restrict__ lnb,
    unsigned short* __restrict__ hnb,         /* next-layer LN out, bf16 */
    int last){
  __shared__ __align__(16) unsigned short Vsh[32*VP];     /* 49664 B; f32 partial alias */
  __shared__ float rowsqW[16][32];
  __shared__ float rowsq[32];
  __shared__ float rsumW[8][32], rsqW[8][32], mu_s[32], rs_s[32];
  const int tid = threadIdx.x;
  const int c = blockIdx.x & 31, b = blockIdx.x >> 5;
  const int t0 = c*CHUNK;
  const int rt0 = (b*SEQ + t0) >> 4;
  const int wave = tid >> 6, lane = tid & 63;
  const int lq = lane >> 4, lm = lane & 15;
  const f32x4_t zero = (f32x4_t){0.f,0.f,0.f,0.f};

  /* ---- phase 1: V = (y + cum*C@Hin^T)*silu(z) -> Vsh; 2 waves/head (pt-halves) - */
  {
    float sql[2][4] = {};
    const int h = wave >> 1;
    const int pt0 = (wave & 1)*3;
    float cumv[2][4];
    {
      const float* cbp = cumb + ((size_t)((b*NC + c)*NHEADS) + h)*CHUNK;
      #pragma unroll
      for (int tt=0;tt<2;tt++)
        #pragma unroll
        for (int r=0;r<4;r++)
          cumv[tt][r] = cbp[tt*16 + lq*4 + r];
    }
    const unsigned short* Hb = Hinb + ((size_t)((b*NC + c)*NHEADS) + h)*HEADDIM*D_STATE;
    bf16x8_t ca[2][2];
    #pragma unroll
    for (int tt=0;tt<2;tt++)
      #pragma unroll
      for (int kt=0;kt<2;kt++)
        ca[tt][kt] = *(const bf16x8_t*)(Cb +
            ((size_t)(b*SEQ) + t0 + tt*16 + lm)*D_STATE + kt*32 + lq*8);
    /* hoist all 3 pp iterations' loads: burst-issue, hide L2 latency */
    bf16x8_t hf0a[3], hf1a[3];
    ushort4 yf4a[3][2], zf4a[3][2];
    #pragma unroll
    for (int pp=0; pp<3; pp++){
      int pt = pt0 + pp;
      hf0a[pp] = *(const bf16x8_t*)&Hb[(size_t)(lm+pt*16)*D_STATE + lq*8];
      hf1a[pp] = *(const bf16x8_t*)&Hb[(size_t)(lm+pt*16)*D_STATE + 32 + lq*8];
      #pragma unroll
      for (int tt=0;tt<2;tt++){
        yf4a[pp][tt] = *(const ushort4*)(yfrag + ZFT(rt0+tt, h*6+pt) + lane*4);
        zf4a[pp][tt] = *(const ushort4*)(zfrag + ZFT(rt0+tt, h*6+pt) + lane*4);
      }
    }
    #pragma unroll
    for (int pp=0; pp<3; pp++){
      int pt = pt0 + pp;
      f32x4_t acc[2];
      #pragma unroll
      for (int tt=0;tt<2;tt++){
        acc[tt] = __builtin_amdgcn_mfma_f32_16x16x32_bf16(ca[tt][0], hf0a[pp], zero, 0,0,0);
        acc[tt] = __builtin_amdgcn_mfma_f32_16x16x32_bf16(ca[tt][1], hf1a[pp], acc[tt], 0,0,0);
      }
      int pcol = h*HEADDIM + pt*16 + lm;
      #pragma unroll
      for (int tt=0;tt<2;tt++){
        const unsigned short* yp = (const unsigned short*)&yf4a[pp][tt];
        const unsigned short* zp = (const unsigned short*)&zf4a[pp][tt];
        #pragma unroll
        for (int r=0;r<4;r++){
          int t = tt*16 + lq*4 + r;
          float yv = bits_to_f(yp[r]) + cumv[tt][r]*acc[tt][r];
          float z  = bits_to_f(zp[r]);
          float v  = yv * silu_f(z);
          Vsh[t*VP + pcol] = f_to_bits(v);
          sql[tt][r] += v*v;
        }
      }
    }
    /* per-wave slots: no atomics, no init */
    #pragma unroll
    for (int tt=0;tt<2;tt++)
      #pragma unroll
      for (int r=0;r<4;r++){
        float v = sql[tt][r];
        v += __shfl_xor(v,1); v += __shfl_xor(v,2);
        v += __shfl_xor(v,4); v += __shfl_xor(v,8);
        if (lm == 0) rowsqW[wave][tt*16 + lq*4 + r] = v;
      }
  }
  __syncthreads();
  if (tid < 32){
    float s = 0.f;
    #pragma unroll
    for (int w=0;w<16;w++) s += rowsqW[w][tid];
    rowsq[tid] = rsqrtf(s*(1.f/D_INNER) + 1e-5f);
  }
  __syncthreads();

  /* ---- phase 2: delta(32x384) = Vsh(32x768) @ Wot^T; 8 col-groups x 2 k-halves - */
  const int w8 = wave & 7, kh = wave >> 3;
  const int wn = w8*48;
  const int kbase = kh*384;
  f32x4_t acc[2][3];
  #pragma unroll
  for (int i=0;i<2;i++)
    #pragma unroll
    for (int j=0;j<3;j++)
      acc[i][j] = zero;
  {
    bf16x8_t afA[2], afB[2], bfA[3], bfB[3];
#define LOADK(af_, bf_, K0) { \
    af_[0] = *(const bf16x8_t*)&Vsh[(     lm)*VP + (K0) + lq*8]; \
    af_[1] = *(const bf16x8_t*)&Vsh[(16 + lm)*VP + (K0) + lq*8]; \
    bf_[0] = *(const bf16x8_t*)(Wot + (size_t)(wn      + lm)*D_INNER + (K0) + lq*8); \
    bf_[1] = *(const bf16x8_t*)(Wot + (size_t)(wn + 16 + lm)*D_INNER + (K0) + lq*8); \
    bf_[2] = *(const bf16x8_t*)(Wot + (size_t)(wn + 32 + lm)*D_INNER + (K0) + lq*8); \
  }
    LOADK(afA, bfA, kbase)
    #pragma unroll
    for (int ks=0; ks<12; ks+=2){
      LOADK(afB, bfB, kbase + (ks+1)*32)
      #pragma unroll
      for (int i=0;i<2;i++)
        #pragma unroll
        for (int j=0;j<3;j++)
          acc[i][j] = __builtin_amdgcn_mfma_f32_16x16x32_bf16(afA[i], bfA[j], acc[i][j], 0,0,0);
      if (ks+2 < 12) LOADK(afA, bfA, kbase + (ks+2)*32)
      #pragma unroll
      for (int i=0;i<2;i++)
        #pragma unroll
        for (int j=0;j<3;j++)
          acc[i][j] = __builtin_amdgcn_mfma_f32_16x16x32_bf16(afB[i], bfB[j], acc[i][j], 0,0,0);
    }
#undef LOADK
  }
  /* partial-sum reduce: kh=1 waves park partials in Vsh alias; kh=0 waves add */
  __syncthreads();                       /* all Vsh reads of phase 2 complete */
  {
    float* pr = (float*)Vsh;             /* 12288 floats = 48 KB */
    const int idx = (w8*64 + lane)*24;
    if (kh == 1){
      #pragma unroll
      for (int tt=0;tt<2;tt++)
        #pragma unroll
        for (int j=0;j<3;j++)
          #pragma unroll
          for (int r=0;r<4;r++)
            pr[idx + tt*12 + j*4 + r] = acc[tt][j][r];
    }
    __syncthreads();
    if (kh == 0){
      #pragma unroll
      for (int tt=0;tt<2;tt++)
        #pragma unroll
        for (int j=0;j<3;j++)
          #pragma unroll
          for (int r=0;r<4;r++)
            acc[tt][j][r] += pr[idx + tt*12 + j*4 + r];
    }
  }

  /* ---- phase 3 (waves kh==0): rms scale + residual RMW; LN -> hnb / row-major -- */
  float ov[2][3][4];
  if (kh == 0){
    #pragma unroll
    for (int tt=0;tt<2;tt++)
      #pragma unroll
      for (int j=0;j<3;j++){
        f32x4_t rv = *(const f32x4_t*)(outf + RFT(rt0+tt, w8*3+j) + lane*4);
        #pragma unroll
        for (int r=0;r<4;r++){
          float rms = rowsq[tt*16 + lq*4 + r];
          ov[tt][j][r] = rv[r] + acc[tt][j][r]*rms;
        }
      }
  }

  if (last){
    __syncthreads();   /* all fragment reads done before row-major writes to slab */
    if (kh == 0){
      #pragma unroll
      for (int tt=0;tt<2;tt++)
        #pragma unroll
        for (int r=0;r<4;r++){
          size_t row = (size_t)(b*SEQ) + t0 + tt*16 + lq*4 + r;
          #pragma unroll
          for (int j=0;j<3;j++)
            outf[row*D_MODEL + wn + j*16 + lm] = ov[tt][j][r];
        }
    }
    return;
  }

  if (kh == 0){
    #pragma unroll
    for (int tt=0;tt<2;tt++)
      #pragma unroll
      for (int j=0;j<3;j++){
        f32x4_t rv;
        #pragma unroll
        for (int r=0;r<4;r++) rv[r] = ov[tt][j][r];
        *(f32x4_t*)(outf + RFT(rt0+tt, w8*3+j) + lane*4) = rv;
      }
    /* LN stats into per-wave slots (no atomics) */
    #pragma unroll
    for (int tt=0;tt<2;tt++){
      #pragma unroll
      for (int r=0;r<4;r++){
        int t = tt*16 + lq*4 + r;
        float s = 0.f, sq = 0.f;
        #pragma unroll
        for (int j=0;j<3;j++){ float o = ov[tt][j][r]; s += o; sq += o*o; }
        s  += __shfl_xor(s,1);  s  += __shfl_xor(s,2);  s  += __shfl_xor(s,4);  s  += __shfl_xor(s,8);
        sq += __shfl_xor(sq,1); sq += __shfl_xor(sq,2); sq += __shfl_xor(sq,4); sq += __shfl_xor(sq,8);
        if (lm == 0){ rsumW[w8][t] = s; rsqW[w8][t] = sq; }
      }
    }
  }
  __syncthreads();
  if (tid < 32){
    float s = 0.f, sq = 0.f;
    #pragma unroll
    for (int w=0;w<8;w++){ s += rsumW[w][tid]; sq += rsqW[w][tid]; }
    float mu  = s*(1.f/D_MODEL);
    float var = sq*(1.f/D_MODEL) - mu*mu;
    var = var < 0.f ? 0.f : var;
    mu_s[tid] = mu;
    rs_s[tid] = rsqrtf(var + 1e-12f);
  }
  __syncthreads();
  if (kh == 0){
    #pragma unroll
    for (int tt=0;tt<2;tt++){
      #pragma unroll
      for (int r=0;r<4;r++){
        int t = tt*16 + lq*4 + r;
        size_t row = (size_t)(b*SEQ) + t0 + t;
        float mu = mu_s[t], rs = rs_s[t];
        #pragma unroll
        for (int j=0;j<3;j++){
          int n = wn + j*16 + lm;
          hnb[row*D_MODEL + n] = f_to_bits((ov[tt][j][r]-mu)*rs*lnw[n] + lnb[n]);
        }
      }
    }
  }
}

extern "C" void kernel_launch(void* const* d_in, const int* in_sizes, int n_in,
                              void* d_out, int out_size, void* d_ws, size_t ws_size,
                              hipStream_t stream){
  const float* x0      = (const float*)d_in[0];
  const float* ln_w    = (const float*)d_in[1];
  const float* ln_b    = (const float*)d_in[2];
  const float* W_in    = (const float*)d_in[3];
  const float* conv_w  = (const float*)d_in[4];
  const float* conv_b  = (const float*)d_in[5];
  const float* dt_bias = (const float*)d_in[6];
  const float* A_log   = (const float*)d_in[7];
  const float* D_skip  = (const float*)d_in[8];
  const float* norm_w  = (const float*)d_in[9];
  const float* W_out   = (const float*)d_in[10];
  float* out = (float*)d_out;

  /* workspace (float units), ~85 MB */
  float* p    = (float*)d_ws;
  unsigned short* xbc   = (unsigned short*)p; p += (size_t)ROWS*XBC_LD/2;
  float* dtraw = p;  p += (size_t)ROWS*8;
  float* cumb  = p;  p += (size_t)BATCH*NHEADS*SEQ;
  float* Dc    = p;  p += (size_t)BATCH*NHEADS*NC;
  unsigned short* yfrag = (unsigned short*)p; p += (size_t)ROWS*D_INNER/2;
  unsigned short* zfrag = (unsigned short*)p; p += (size_t)ROWS*D_INNER/2;
  unsigned short* hnb   = (unsigned short*)p; p += (size_t)ROWS*D_MODEL/2;
  unsigned short* Sb    = (unsigned short*)p; p += (size_t)BATCH*NC*NHEADS*HEADDIM*D_STATE/2;
  unsigned short* Cb    = (unsigned short*)p; p += (size_t)ROWS*D_STATE/2;
  bf16* Wt  = (bf16*)p; p += (size_t)NUM_LAYERS*NPAD_IN*D_MODEL/2;
  bf16* Wot = (bf16*)p;

  wconv_kernel<<<dim3(NPAD_IN/32, D_MODEL/32, NUM_LAYERS), dim3(32,8), 0, stream>>>(
      W_in, Wt, nullptr, D_MODEL, D_IN_PROJ, NPAD_IN);
  /* fold norm_w into W_out rows (k = D_INNER dim) */
  wconv_kernel<<<dim3(NPAD_OUT/32, D_INNER/32, NUM_LAYERS), dim3(32,8), 0, stream>>>(
      W_out, Wot, norm_w, D_INNER, D_MODEL, NPAD_OUT);

  /* residual stream -> fragment blob inside d_out; layer-0 LN from x0 */
  xfrag_kernel<<<(ROWS/16)*24/4, 256, 0, stream>>>(x0, out);
  ln_kernel<<<ROWS/4,256,0,stream>>>(x0, ln_w, ln_b, hnb);

  for (int i=0;i<NUM_LAYERS;i++){
    int last = (i == NUM_LAYERS-1);
    gemm_in<<<dim3(14, ROWS/256), 256, 0, stream>>>(
        (const unsigned short*)hnb, (const unsigned short*)(Wt + (size_t)i*NPAD_IN*D_MODEL),
        zfrag, xbc, dtraw, D_MODEL);
    fused_scan_kernel<<<BATCH*NC*4, 256, 0, stream>>>(
        xbc, dtraw, conv_w + (size_t)i*CONV_DIM*4, conv_b + (size_t)i*CONV_DIM,
        dt_bias+(size_t)i*NHEADS, A_log+(size_t)i*NHEADS, D_skip+(size_t)i*NHEADS,
        cumb, Dc, Cb, Sb, yfrag);
    combine_kernel<<<(BATCH*NHEADS*HEADDIM*32)/256, 256, 0, stream>>>(Sb, Dc);
    hinfuse_out_kernel<<<BATCH*NC, 1024, 0, stream>>>(
        Cb, Sb, cumb, zfrag, yfrag,
        (const unsigned short*)(Wot + (size_t)i*NPAD_OUT*D_INNER), out,
        ln_w + (size_t)(last ? i : i+1)*D_MODEL,
        ln_b + (size_t)(last ? i : i+1)*D_MODEL,
        hnb, last);
  }
}